// Round 1
// baseline (169.678 us; speedup 1.0000x reference)
//
#include <hip/hip_runtime.h>
#include <cmath>

constexpr int H = 256, W = 256;
constexpr int PSIZE = 16, PSTRIDE = 8;
constexpr int NUMS = 31;               // (H-PSIZE)/PSTRIDE + 1
constexpr int L = NUMS * NUMS;         // 961
constexpr int B = 2, C = 64;
constexpr float EPS = 1e-5f;
constexpr int CH = 16;                 // row-chunks for global stats
constexpr int NL = 8;                  // query rows per attention block
constexpr int NGROUP = (L + NL - 1) / NL; // 121

// ---------------------------------------------------------------------------
// Kernel 1a: partial global moments per (b,c,chunk).
// partials[(bc*CH+chunk)*5 + {0..4}] = {Sx_bg, Sxx_bg, Sx_all, Sxx_all, Nfg}
// ---------------------------------------------------------------------------
__global__ __launch_bounds__(256) void stats_part_kernel(
    const float* __restrict__ x, const float* __restrict__ mask,
    float* __restrict__ partials)
{
    int gid = blockIdx.x;              // bc*CH + chunk
    int chunk = gid % CH, bc = gid / CH;
    int b = bc / C;
    const float* xp = x + (size_t)bc * (H * W) + (size_t)chunk * (H * W / CH);
    const float* mp = mask + (size_t)b * (H * W) + (size_t)chunk * (H * W / CH);
    int t = threadIdx.x;

    float sxbg = 0.f, sxxbg = 0.f, sxall = 0.f, sxxall = 0.f, nfg = 0.f;
    for (int i = t; i < (H * W / CH) / 4; i += 256) {
        float4 xv = ((const float4*)xp)[i];
        float4 mv = ((const float4*)mp)[i];
        float xs[4] = {xv.x, xv.y, xv.z, xv.w};
        float ms[4] = {mv.x, mv.y, mv.z, mv.w};
#pragma unroll
        for (int j = 0; j < 4; ++j) {
            float xx = xs[j], m = ms[j], om = 1.0f - m;
            sxall += xx; sxxall += xx * xx;
            sxbg += xx * om; sxxbg += xx * xx * om;
            nfg += m;
        }
    }
    __shared__ float red[5][256];
    red[0][t] = sxbg; red[1][t] = sxxbg; red[2][t] = sxall;
    red[3][t] = sxxall; red[4][t] = nfg;
    __syncthreads();
    for (int off = 128; off; off >>= 1) {
        if (t < off) {
#pragma unroll
            for (int j = 0; j < 5; ++j) red[j][t] += red[j][t + off];
        }
        __syncthreads();
    }
    if (t < 5) partials[(size_t)gid * 5 + t] = red[t][0];
}

// ---------------------------------------------------------------------------
// Kernel 1b: finalize stats[bc*4 + {mu_b, std_b, mu_f, std_f}]
// ---------------------------------------------------------------------------
__global__ __launch_bounds__(128) void stats_final_kernel(
    const float* __restrict__ partials, float* __restrict__ stats)
{
    int bc = threadIdx.x;
    if (bc >= B * C) return;
    float s0 = 0.f, s1 = 0.f, s2 = 0.f, s3 = 0.f, s4 = 0.f;
    for (int ch = 0; ch < CH; ++ch) {
        const float* p = partials + ((size_t)bc * CH + ch) * 5;
        s0 += p[0]; s1 += p[1]; s2 += p[2]; s3 += p[3]; s4 += p[4];
    }
    float nfg = s4;
    float numbg = (float)(H * W) - nfg;
    float mu_b = s0 / (numbg + EPS);
    float var_b = (s1 - 2.f * mu_b * s0 + mu_b * mu_b * numbg) / (numbg + EPS);
    float std_b = sqrtf(var_b + EPS);
    float sxfg = s2 - s0, sxxfg = s3 - s1;
    float mu_f = sxfg / (nfg + EPS);
    float var_f = (sxxfg - 2.f * mu_f * sxfg + mu_f * mu_f * nfg) / (nfg + EPS);
    float std_f = sqrtf(var_f + EPS);
    stats[bc * 4 + 0] = mu_b;
    stats[bc * 4 + 1] = std_b;
    stats[bc * 4 + 2] = mu_f;
    stats[bc * 4 + 3] = std_f;
}

// ---------------------------------------------------------------------------
// Kernel 2: per-patch stats. One block per (b,l); 4 waves cover 64 channels.
// Each lane holds one float4 (4 pixels) of the 16x16 patch.
// Outputs laid out [B][L][C] (coalesced for attention kernel).
// ---------------------------------------------------------------------------
__global__ __launch_bounds__(256) void patch_kernel(
    const float* __restrict__ x, const float* __restrict__ mask,
    const float* __restrict__ stats,
    const float* __restrict__ qg, const float* __restrict__ qbeta,
    const float* __restrict__ kg, const float* __restrict__ kbeta,
    float* __restrict__ qT, float* __restrict__ kT,
    float* __restrict__ mu1T, float* __restrict__ var1T)
{
    int bl = blockIdx.x;
    int b = bl / L, l = bl % L;
    int lh = l / NUMS, lw = l % NUMS;
    int t = threadIdx.x, wave = t >> 6, lane = t & 63;
    int r = lane >> 2, cg = lane & 3;
    int row = lh * PSTRIDE + r, col = lw * PSTRIDE + cg * 4;

    float4 mv = *(const float4*)&mask[((size_t)b * H + row) * W + col];
    float om0 = 1.f - mv.x, om1 = 1.f - mv.y, om2 = 1.f - mv.z, om3 = 1.f - mv.w;
    float nfg = mv.x + mv.y + mv.z + mv.w;
#pragma unroll
    for (int off = 32; off; off >>= 1) nfg += __shfl_xor(nfg, off);
    float numbg = 256.f - nfg;
    float rb = 1.f / (numbg + EPS), rf = 1.f / (nfg + EPS);

    for (int c = wave; c < C; c += 4) {
        float4 xv = *(const float4*)&x[(((size_t)b * C + c) * H + row) * W + col];
        float sxbg = xv.x * om0 + xv.y * om1 + xv.z * om2 + xv.w * om3;
        float sxxbg = xv.x * xv.x * om0 + xv.y * xv.y * om1
                    + xv.z * xv.z * om2 + xv.w * xv.w * om3;
        float sxall = xv.x + xv.y + xv.z + xv.w;
#pragma unroll
        for (int off = 32; off; off >>= 1) {
            sxbg  += __shfl_xor(sxbg, off);
            sxxbg += __shfl_xor(sxxbg, off);
            sxall += __shfl_xor(sxall, off);
        }
        if (lane == 0) {
            const float* st = stats + ((size_t)b * C + c) * 4;
            float mu_b = st[0], std_b = st[1], mu_f = st[2], std_f = st[3];
            float mu1 = sxbg * rb;
            float var1 = (sxxbg - 2.f * mu1 * sxbg + mu1 * mu1 * numbg) * rb;
            float mu4 = (sxbg - mu_b * numbg) / std_b * rb;
            float sxfg = sxall - sxbg;
            float mu3 = (sxfg - mu_f * nfg) / std_f * rf;
            size_t o = ((size_t)b * L + l) * C + c;
            qT[o] = mu3 * qg[c] + qbeta[c];
            kT[o] = mu4 * kg[c] + kbeta[c];
            mu1T[o] = mu1;
            var1T[o] = var1;
        }
    }
}

// ---------------------------------------------------------------------------
// Kernel 3: attention. Block handles NL=8 query patches of one b.
// scores -> per-row softmax (one wave per row) -> S @ {mu1, var1}.
// ---------------------------------------------------------------------------
__global__ __launch_bounds__(256) void attn_kernel(
    const float* __restrict__ qT, const float* __restrict__ kT,
    const float* __restrict__ mu1T, const float* __restrict__ var1T,
    const float* __restrict__ bias_table,
    float* __restrict__ pbT, float* __restrict__ psT)
{
    __shared__ float qv[NL][C];      // 2 KB
    __shared__ float sc[NL][L];      // 30.8 KB
    __shared__ float pbp[4][NL][C];  // 8 KB
    __shared__ float psp[4][NL][C];  // 8 KB

    int gid = blockIdx.x;
    int b = gid / NGROUP;
    int l0 = (gid % NGROUP) * NL;
    int nl = min(NL, L - l0);
    int t = threadIdx.x;

    for (int i = t; i < NL * C; i += 256) {
        int li = i / C, c = i % C;
        int l = min(l0 + li, L - 1);            // clamp tail (writes gated later)
        qv[li][c] = qT[((size_t)b * L + l) * C + c];
    }
    __syncthreads();

    // scores: thread owns m = t, t+256, ...
    for (int m = t; m < L; m += 256) {
        float dot[NL];
#pragma unroll
        for (int li = 0; li < NL; ++li) dot[li] = 0.f;
        const float* kp = kT + ((size_t)b * L + m) * C;
#pragma unroll
        for (int c4 = 0; c4 < C; c4 += 4) {
            float4 kv = *(const float4*)(kp + c4);
#pragma unroll
            for (int li = 0; li < NL; ++li) {
                float4 q4 = *(const float4*)&qv[li][c4];
                dot[li] += q4.x * kv.x + q4.y * kv.y + q4.z * kv.z + q4.w * kv.w;
            }
        }
        int mh = m / NUMS, mw = m % NUMS;
#pragma unroll
        for (int li = 0; li < NL; ++li) {
            int l = min(l0 + li, L - 1);
            int lh = l / NUMS, lw = l % NUMS;
            float bias = bias_table[(lh - mh + NUMS - 1) * (2 * NUMS - 1)
                                    + (lw - mw + NUMS - 1)];
            sc[li][m] = dot[li] + bias;
        }
    }
    __syncthreads();

    // per-row softmax: wave w handles rows w, w+4 (wave-local, no block sync)
    int wave = t >> 6, lane = t & 63;
    for (int li = wave; li < NL; li += 4) {
        float lmax = -1e30f;
        for (int m = lane; m < L; m += 64) lmax = fmaxf(lmax, sc[li][m]);
#pragma unroll
        for (int off = 32; off; off >>= 1) lmax = fmaxf(lmax, __shfl_xor(lmax, off));
        float lsum = 0.f;
        for (int m = lane; m < L; m += 64) {
            float e = expf(sc[li][m] - lmax);
            sc[li][m] = e;
            lsum += e;
        }
#pragma unroll
        for (int off = 32; off; off >>= 1) lsum += __shfl_xor(lsum, off);
        float rs = 1.0f / lsum;
        for (int m = lane; m < L; m += 64) sc[li][m] *= rs;
    }
    __syncthreads();

    // S @ mu1, S @ var1. thread = (chunk, c); coalesced over c per wave.
    int c = t & (C - 1);
    int chunk = t >> 6;
    float pbr[NL], psr[NL];
#pragma unroll
    for (int li = 0; li < NL; ++li) { pbr[li] = 0.f; psr[li] = 0.f; }
    for (int m = chunk; m < L; m += 4) {
        size_t o = ((size_t)b * L + m) * C + c;
        float v1 = mu1T[o], v2 = var1T[o];
#pragma unroll
        for (int li = 0; li < NL; ++li) {
            float wgt = sc[li][m];
            pbr[li] += wgt * v1;
            psr[li] += wgt * v2;
        }
    }
#pragma unroll
    for (int li = 0; li < NL; ++li) { pbp[chunk][li][c] = pbr[li]; psp[chunk][li][c] = psr[li]; }
    __syncthreads();
    for (int i = t; i < nl * C; i += 256) {
        int li = i >> 6, cc = i & 63;
        float vb = pbp[0][li][cc] + pbp[1][li][cc] + pbp[2][li][cc] + pbp[3][li][cc];
        float vs = psp[0][li][cc] + psp[1][li][cc] + psp[2][li][cc] + psp[3][li][cc];
        size_t o = ((size_t)b * L + (l0 + li)) * C + cc;
        pbT[o] = vb;
        psT[o] = vs;
    }
}

// ---------------------------------------------------------------------------
// Kernel 4: fused epilogue. fold == per-pixel sum over covering patches.
// One block per (b,c,h) image row; thread = column.
// ---------------------------------------------------------------------------
__global__ __launch_bounds__(256) void out_kernel(
    const float* __restrict__ x, const float* __restrict__ mask,
    const float* __restrict__ stats,
    const float* __restrict__ pbT, const float* __restrict__ psT,
    const float* __restrict__ fgg, const float* __restrict__ fgb,
    const float* __restrict__ bgg, const float* __restrict__ bgb,
    float* __restrict__ out)
{
    int rid = blockIdx.x;             // (b*C + c)*H + h
    int h = rid & (H - 1);
    int bc = rid / H;
    int c = bc & (C - 1);
    int b = bc >> 6;
    int w = threadIdx.x;
    size_t pix = (size_t)rid * W + w;

    float xv = x[pix];
    float m = mask[((size_t)b * H + h) * W + w];
    const float* st = stats + (size_t)bc * 4;
    float mu_f = st[2], std_f = st[3];
    float nfg_px = (xv - mu_f) / std_f * m;

    int hq = h >> 3, wq = w >> 3;
    int ph0 = hq > 0 ? hq - 1 : 0;
    int ph1 = hq < NUMS ? hq : NUMS - 1;
    int pw0 = wq > 0 ? wq - 1 : 0;
    int pw1 = wq < NUMS ? wq : NUMS - 1;

    float sstd = 0.f, sback = 0.f, cnt = 0.f;
    for (int ph = ph0; ph <= ph1; ++ph)
        for (int pw = pw0; pw <= pw1; ++pw) {
            size_t o = ((size_t)b * L + ph * NUMS + pw) * C + c;
            sstd += psT[o];
            sback += pbT[o];
            cnt += 1.f;
        }
    float nf = (nfg_px * sstd + sback) / cnt;
    float res = (nf * (1.f + fgg[c]) + fgb[c]) * m
              + (xv * (1.f + bgg[c]) + bgb[c]) * (1.f - m);
    out[pix] = res;
}

// ---------------------------------------------------------------------------
extern "C" void kernel_launch(void* const* d_in, const int* in_sizes, int n_in,
                              void* d_out, int out_size, void* d_ws, size_t ws_size,
                              hipStream_t stream)
{
    const float* x    = (const float*)d_in[0];
    const float* mask = (const float*)d_in[1];
    const float* fgg  = (const float*)d_in[2];
    const float* fgb  = (const float*)d_in[3];
    const float* bgg  = (const float*)d_in[4];
    const float* bgb  = (const float*)d_in[5];
    const float* qg   = (const float*)d_in[6];
    const float* qb   = (const float*)d_in[7];
    const float* kg   = (const float*)d_in[8];
    const float* kb   = (const float*)d_in[9];
    const float* bt   = (const float*)d_in[10];
    float* out = (float*)d_out;

    float* ws = (float*)d_ws;
    const size_t BLC = (size_t)B * L * C;     // 123008
    float* partials = ws;                     // B*C*CH*5 = 10240
    float* stats    = partials + (size_t)B * C * CH * 5;  // 512
    float* qT    = stats + B * C * 4;
    float* kT    = qT + BLC;
    float* mu1T  = kT + BLC;
    float* var1T = mu1T + BLC;
    float* pbT   = var1T + BLC;
    float* psT   = pbT + BLC;

    stats_part_kernel<<<B * C * CH, 256, 0, stream>>>(x, mask, partials);
    stats_final_kernel<<<1, 128, 0, stream>>>(partials, stats);
    patch_kernel<<<B * L, 256, 0, stream>>>(x, mask, stats, qg, qb, kg, kb,
                                            qT, kT, mu1T, var1T);
    attn_kernel<<<B * NGROUP, 256, 0, stream>>>(qT, kT, mu1T, var1T, bt, pbT, psT);
    out_kernel<<<B * C * H, 256, 0, stream>>>(x, mask, stats, pbT, psT,
                                              fgg, fgb, bgg, bgb, out);
}

// Round 2
// 127.142 us; speedup vs baseline: 1.3346x; 1.3346x over previous
//
#include <hip/hip_runtime.h>
#include <cmath>

constexpr int H = 256, W = 256;
constexpr int PSIZE = 16, PSTRIDE = 8;
constexpr int NUMS = 31;               // (H-PSIZE)/PSTRIDE + 1
constexpr int L = NUMS * NUMS;         // 961
constexpr int B = 2, C = 64;
constexpr float EPS = 1e-5f;
constexpr int CH = 16;                 // row-chunks for global stats

constexpr int NL = 4;                  // query rows per attention block
constexpr int NGROUP = (L + NL - 1) / NL;   // 241
constexpr int LP = NGROUP * NL;             // 964 (padded rows)
constexpr int MSPLIT = 4;                   // m-dimension slices
constexpr int MSL = (L + MSPLIT - 1) / MSPLIT; // 241

// ---------------------------------------------------------------------------
// Kernel 1a: partial global moments per (b,c,chunk).
// partials[(bc*CH+chunk)*5 + {0..4}] = {Sx_bg, Sxx_bg, Sx_all, Sxx_all, Nfg}
// ---------------------------------------------------------------------------
__global__ __launch_bounds__(256) void stats_part_kernel(
    const float* __restrict__ x, const float* __restrict__ mask,
    float* __restrict__ partials)
{
    int gid = blockIdx.x;              // bc*CH + chunk
    int chunk = gid % CH, bc = gid / CH;
    int b = bc / C;
    const float* xp = x + (size_t)bc * (H * W) + (size_t)chunk * (H * W / CH);
    const float* mp = mask + (size_t)b * (H * W) + (size_t)chunk * (H * W / CH);
    int t = threadIdx.x;

    float sxbg = 0.f, sxxbg = 0.f, sxall = 0.f, sxxall = 0.f, nfg = 0.f;
    for (int i = t; i < (H * W / CH) / 4; i += 256) {
        float4 xv = ((const float4*)xp)[i];
        float4 mv = ((const float4*)mp)[i];
        float xs[4] = {xv.x, xv.y, xv.z, xv.w};
        float ms[4] = {mv.x, mv.y, mv.z, mv.w};
#pragma unroll
        for (int j = 0; j < 4; ++j) {
            float xx = xs[j], m = ms[j], om = 1.0f - m;
            sxall += xx; sxxall += xx * xx;
            sxbg += xx * om; sxxbg += xx * xx * om;
            nfg += m;
        }
    }
    __shared__ float red[5][256];
    red[0][t] = sxbg; red[1][t] = sxxbg; red[2][t] = sxall;
    red[3][t] = sxxall; red[4][t] = nfg;
    __syncthreads();
    for (int off = 128; off; off >>= 1) {
        if (t < off) {
#pragma unroll
            for (int j = 0; j < 5; ++j) red[j][t] += red[j][t + off];
        }
        __syncthreads();
    }
    if (t < 5) partials[(size_t)gid * 5 + t] = red[t][0];
}

// ---------------------------------------------------------------------------
// Kernel 1b: finalize stats[bc*4 + {mu_b, std_b, mu_f, std_f}]
// ---------------------------------------------------------------------------
__global__ __launch_bounds__(128) void stats_final_kernel(
    const float* __restrict__ partials, float* __restrict__ stats)
{
    int bc = threadIdx.x;
    if (bc >= B * C) return;
    float s0 = 0.f, s1 = 0.f, s2 = 0.f, s3 = 0.f, s4 = 0.f;
    for (int ch = 0; ch < CH; ++ch) {
        const float* p = partials + ((size_t)bc * CH + ch) * 5;
        s0 += p[0]; s1 += p[1]; s2 += p[2]; s3 += p[3]; s4 += p[4];
    }
    float nfg = s4;
    float numbg = (float)(H * W) - nfg;
    float mu_b = s0 / (numbg + EPS);
    float var_b = (s1 - 2.f * mu_b * s0 + mu_b * mu_b * numbg) / (numbg + EPS);
    float std_b = sqrtf(var_b + EPS);
    float sxfg = s2 - s0, sxxfg = s3 - s1;
    float mu_f = sxfg / (nfg + EPS);
    float var_f = (sxxfg - 2.f * mu_f * sxfg + mu_f * mu_f * nfg) / (nfg + EPS);
    float std_f = sqrtf(var_f + EPS);
    stats[bc * 4 + 0] = mu_b;
    stats[bc * 4 + 1] = std_b;
    stats[bc * 4 + 2] = mu_f;
    stats[bc * 4 + 3] = std_f;
}

// ---------------------------------------------------------------------------
// Kernel 2: per-patch stats. One block per (b,l). lane = channel, so NO
// cross-lane reduction; wave w covers patch rows 4w..4w+3, LDS combine.
// Outputs laid out [B][L][C] (coalesced for attention kernel).
// ---------------------------------------------------------------------------
__global__ __launch_bounds__(256) void patch_kernel(
    const float* __restrict__ x, const float* __restrict__ mask,
    const float* __restrict__ stats,
    const float* __restrict__ qg, const float* __restrict__ qbeta,
    const float* __restrict__ kg, const float* __restrict__ kbeta,
    float* __restrict__ qT, float* __restrict__ kT,
    float* __restrict__ mu1T, float* __restrict__ var1T)
{
    int bl = blockIdx.x;
    int b = bl / L, l = bl % L;
    int lh = l / NUMS, lw = l % NUMS;
    int t = threadIdx.x, wave = t >> 6, c = t & 63;
    int row0 = lh * PSTRIDE + wave * 4, col0 = lw * PSTRIDE;

    const float* xp = x + (size_t)(b * C + c) * (H * W);
    const float* mp = mask + (size_t)b * (H * W);

    float sxbg = 0.f, sxxbg = 0.f, sxall = 0.f, nfg = 0.f;
#pragma unroll
    for (int r = 0; r < 4; ++r) {
        size_t ro = (size_t)(row0 + r) * W + col0;
#pragma unroll
        for (int q = 0; q < 4; ++q) {
            float4 xv = *(const float4*)&xp[ro + q * 4];
            float4 mv = *(const float4*)&mp[ro + q * 4];   // broadcast per wave
            float om0 = 1.f - mv.x, om1 = 1.f - mv.y;
            float om2 = 1.f - mv.z, om3 = 1.f - mv.w;
            sxall += xv.x + xv.y + xv.z + xv.w;
            sxbg  += xv.x * om0 + xv.y * om1 + xv.z * om2 + xv.w * om3;
            sxxbg += xv.x * xv.x * om0 + xv.y * xv.y * om1
                   + xv.z * xv.z * om2 + xv.w * xv.w * om3;
            nfg   += mv.x + mv.y + mv.z + mv.w;
        }
    }
    __shared__ float red[4][4][64];    // [var][wave][c]
    red[0][wave][c] = sxbg; red[1][wave][c] = sxxbg;
    red[2][wave][c] = sxall; red[3][wave][c] = nfg;
    __syncthreads();
    if (t < 64) {
        float sb  = red[0][0][c] + red[0][1][c] + red[0][2][c] + red[0][3][c];
        float sxx = red[1][0][c] + red[1][1][c] + red[1][2][c] + red[1][3][c];
        float sa  = red[2][0][c] + red[2][1][c] + red[2][2][c] + red[2][3][c];
        float nf  = red[3][0][c] + red[3][1][c] + red[3][2][c] + red[3][3][c];
        float numbg = 256.f - nf;
        float rb = 1.f / (numbg + EPS), rf = 1.f / (nf + EPS);
        const float* st = stats + ((size_t)b * C + c) * 4;
        float mu_b = st[0], std_b = st[1], mu_f = st[2], std_f = st[3];
        float mu1 = sb * rb;
        float var1 = (sxx - 2.f * mu1 * sb + mu1 * mu1 * numbg) * rb;
        float mu4 = (sb - mu_b * numbg) / std_b * rb;
        float sxfg = sa - sb;
        float mu3 = (sxfg - mu_f * nf) / std_f * rf;
        size_t o = ((size_t)b * L + l) * C + c;
        qT[o] = mu3 * qg[c] + qbeta[c];
        kT[o] = mu4 * kg[c] + kbeta[c];
        mu1T[o] = mu1;
        var1T[o] = var1;
    }
}

// ---------------------------------------------------------------------------
// Kernel 3a: attention partials. Block = (m-slice ms, batch b, l-group g).
// Max-free softmax: e = exp(score) directly (scores are O(0.1)), so the
// m-dimension decomposes. Partial sums of e, e*mu1, e*var1 per slice.
// ---------------------------------------------------------------------------
__global__ __launch_bounds__(256) void attn_part_kernel(
    const float* __restrict__ qT, const float* __restrict__ kT,
    const float* __restrict__ mu1T, const float* __restrict__ var1T,
    const float* __restrict__ bias_table,
    float* __restrict__ pbP, float* __restrict__ psP, float* __restrict__ rsP)
{
    __shared__ float qv[NL][C];        // 1 KB
    __shared__ float sc[NL][MSL];      // 3.8 KB
    __shared__ float pbp[4][NL][C];    // 4 KB
    __shared__ float psp[4][NL][C];    // 4 KB
    __shared__ float rred[NL][4];

    int gid = blockIdx.x;              // (ms*B + b)*NGROUP + g : same-slice blocks adjacent
    int g = gid % NGROUP;
    int t1 = gid / NGROUP;
    int b = t1 % B, ms = t1 / B;
    int l0 = g * NL;
    int m0 = ms * MSL, m1 = min(m0 + MSL, L);
    int t = threadIdx.x;

    for (int i = t; i < NL * C; i += 256) {
        int li = i >> 6, c = i & 63;
        int l = min(l0 + li, L - 1);
        qv[li][c] = qT[((size_t)b * L + l) * C + c];
    }
    __syncthreads();

    int lhs[NL], lws[NL];
#pragma unroll
    for (int li = 0; li < NL; ++li) {
        int l = min(l0 + li, L - 1);
        lhs[li] = l / NUMS; lws[li] = l % NUMS;
    }

    float psum[NL] = {0.f, 0.f, 0.f, 0.f};
    for (int m = m0 + t; m < m1; m += 256) {
        float dot[NL] = {0.f, 0.f, 0.f, 0.f};
        const float* kp = kT + ((size_t)b * L + m) * C;
#pragma unroll 4
        for (int c4 = 0; c4 < C; c4 += 4) {
            float4 kv = *(const float4*)(kp + c4);
#pragma unroll
            for (int li = 0; li < NL; ++li) {
                float4 q4 = *(const float4*)&qv[li][c4];
                dot[li] += q4.x * kv.x + q4.y * kv.y + q4.z * kv.z + q4.w * kv.w;
            }
        }
        int mh = m / NUMS, mw = m % NUMS;
#pragma unroll
        for (int li = 0; li < NL; ++li) {
            float bias = bias_table[(lhs[li] - mh + NUMS - 1) * (2 * NUMS - 1)
                                    + (lws[li] - mw + NUMS - 1)];
            float e = __expf(dot[li] + bias);
            sc[li][m - m0] = e;
            psum[li] += e;
        }
    }
    int wave = t >> 6, lane = t & 63;
#pragma unroll
    for (int li = 0; li < NL; ++li) {
        float v = psum[li];
#pragma unroll
        for (int off = 32; off; off >>= 1) v += __shfl_xor(v, off);
        if (lane == 0) rred[li][wave] = v;
    }
    __syncthreads();

    // partial PV over the slice
    int c = t & 63, chunk = t >> 6;
    float pbr[NL] = {0.f, 0.f, 0.f, 0.f}, psr[NL] = {0.f, 0.f, 0.f, 0.f};
    for (int m = m0 + chunk; m < m1; m += 4) {
        size_t o = ((size_t)b * L + m) * C + c;
        float v1 = mu1T[o], v2 = var1T[o];
#pragma unroll
        for (int li = 0; li < NL; ++li) {
            float wgt = sc[li][m - m0];
            pbr[li] += wgt * v1;
            psr[li] += wgt * v2;
        }
    }
#pragma unroll
    for (int li = 0; li < NL; ++li) {
        pbp[chunk][li][c] = pbr[li];
        psp[chunk][li][c] = psr[li];
    }
    __syncthreads();
    if (t < NL * C) {
        int li = t >> 6, cc = t & 63;
        float vb = pbp[0][li][cc] + pbp[1][li][cc] + pbp[2][li][cc] + pbp[3][li][cc];
        float vs = psp[0][li][cc] + psp[1][li][cc] + psp[2][li][cc] + psp[3][li][cc];
        size_t o = (((size_t)ms * B + b) * LP + (l0 + li)) * C + cc;
        pbP[o] = vb;
        psP[o] = vs;
        if (cc == 0)
            rsP[((size_t)ms * B + b) * LP + l0 + li]
                = rred[li][0] + rred[li][1] + rred[li][2] + rred[li][3];
    }
}

// ---------------------------------------------------------------------------
// Kernel 3b: combine m-slices, normalize by total row sum.
// ---------------------------------------------------------------------------
__global__ __launch_bounds__(256) void attn_combine_kernel(
    const float* __restrict__ pbP, const float* __restrict__ psP,
    const float* __restrict__ rsP,
    float* __restrict__ pbT, float* __restrict__ psT)
{
    int idx = blockIdx.x * 256 + threadIdx.x;
    if (idx >= B * L * C) return;
    int c = idx & 63;
    int bl = idx >> 6;
    int l = bl % L, b = bl / L;
    float vb = 0.f, vs = 0.f, rs = 0.f;
#pragma unroll
    for (int ms = 0; ms < MSPLIT; ++ms) {
        size_t o = (((size_t)ms * B + b) * LP + l) * C + c;
        vb += pbP[o];
        vs += psP[o];
        rs += rsP[((size_t)ms * B + b) * LP + l];
    }
    float inv = 1.f / rs;
    size_t o = ((size_t)b * L + l) * C + c;
    pbT[o] = vb * inv;
    psT[o] = vs * inv;
}

// ---------------------------------------------------------------------------
// Kernel 4: fused epilogue, x4 vectorized. All 4 pixels of an aligned quad
// share the same covering-patch set (wq uniform), so gather once.
// ---------------------------------------------------------------------------
__global__ __launch_bounds__(256) void out_kernel(
    const float* __restrict__ x, const float* __restrict__ mask,
    const float* __restrict__ stats,
    const float* __restrict__ pbT, const float* __restrict__ psT,
    const float* __restrict__ fgg, const float* __restrict__ fgb,
    const float* __restrict__ bgg, const float* __restrict__ bgb,
    float* __restrict__ out)
{
    int idx = blockIdx.x * 256 + threadIdx.x;   // one float4 each
    int w4 = idx & (W / 4 - 1);
    int rest = idx >> 6;
    int h = rest & (H - 1);
    int bc = rest >> 8;
    int c = bc & (C - 1);
    int b = bc >> 6;
    int w = w4 * 4;

    size_t pix = ((size_t)bc * H + h) * W + w;
    float4 xv = *(const float4*)&x[pix];
    float4 mv = *(const float4*)&mask[((size_t)b * H + h) * W + w];

    const float* st = stats + (size_t)bc * 4;
    float mu_f = st[2], rstd_f = 1.f / st[3];

    int hq = h >> 3, wq = w >> 3;
    int ph0 = hq > 0 ? hq - 1 : 0;
    int ph1 = hq < NUMS ? hq : NUMS - 1;
    int pw0 = wq > 0 ? wq - 1 : 0;
    int pw1 = wq < NUMS ? wq : NUMS - 1;

    float sstd = 0.f, sback = 0.f, cnt = 0.f;
    for (int ph = ph0; ph <= ph1; ++ph)
        for (int pw = pw0; pw <= pw1; ++pw) {
            size_t o = ((size_t)b * L + ph * NUMS + pw) * C + c;
            sstd += psT[o];
            sback += pbT[o];
            cnt += 1.f;
        }
    float rcnt = 1.f / cnt;
    float ga = 1.f + fgg[c], be = fgb[c];
    float gb_ = 1.f + bgg[c], bb = bgb[c];

    float xs[4] = {xv.x, xv.y, xv.z, xv.w};
    float ms_[4] = {mv.x, mv.y, mv.z, mv.w};
    float4 res;
    float* rp = &res.x;
#pragma unroll
    for (int j = 0; j < 4; ++j) {
        float nfg_px = (xs[j] - mu_f) * rstd_f * ms_[j];
        float nf = (nfg_px * sstd + sback) * rcnt;
        rp[j] = (nf * ga + be) * ms_[j] + (xs[j] * gb_ + bb) * (1.f - ms_[j]);
    }
    *(float4*)&out[pix] = res;
}

// ---------------------------------------------------------------------------
extern "C" void kernel_launch(void* const* d_in, const int* in_sizes, int n_in,
                              void* d_out, int out_size, void* d_ws, size_t ws_size,
                              hipStream_t stream)
{
    const float* x    = (const float*)d_in[0];
    const float* mask = (const float*)d_in[1];
    const float* fgg  = (const float*)d_in[2];
    const float* fgb  = (const float*)d_in[3];
    const float* bgg  = (const float*)d_in[4];
    const float* bgb  = (const float*)d_in[5];
    const float* qg   = (const float*)d_in[6];
    const float* qb   = (const float*)d_in[7];
    const float* kg   = (const float*)d_in[8];
    const float* kb   = (const float*)d_in[9];
    const float* bt   = (const float*)d_in[10];
    float* out = (float*)d_out;

    float* ws = (float*)d_ws;
    const size_t BLC = (size_t)B * L * C;          // 123008
    const size_t PPART = (size_t)MSPLIT * B * LP * C;  // 493568
    float* partials = ws;                          // B*C*CH*5 = 10240
    float* stats    = partials + (size_t)B * C * CH * 5;
    float* qT    = stats + B * C * 4;
    float* kT    = qT + BLC;
    float* mu1T  = kT + BLC;
    float* var1T = mu1T + BLC;
    float* pbT   = var1T + BLC;
    float* psT   = pbT + BLC;
    float* pbP   = psT + BLC;
    float* psP   = pbP + PPART;
    float* rsP   = psP + PPART;                    // MSPLIT*B*LP = 7712

    stats_part_kernel<<<B * C * CH, 256, 0, stream>>>(x, mask, partials);
    stats_final_kernel<<<1, 128, 0, stream>>>(partials, stats);
    patch_kernel<<<B * L, 256, 0, stream>>>(x, mask, stats, qg, qb, kg, kb,
                                            qT, kT, mu1T, var1T);
    attn_part_kernel<<<B * NGROUP * MSPLIT, 256, 0, stream>>>(
        qT, kT, mu1T, var1T, bt, pbP, psP, rsP);
    attn_combine_kernel<<<(B * L * C + 255) / 256, 256, 0, stream>>>(
        pbP, psP, rsP, pbT, psT);
    out_kernel<<<(B * C * H * W / 4 + 255) / 256, 256, 0, stream>>>(
        x, mask, stats, pbT, psT, fgg, fgb, bgg, bgb, out);
}

// Round 4
// 87.953 us; speedup vs baseline: 1.9292x; 1.4456x over previous
//
#include <hip/hip_runtime.h>
#include <hip/hip_fp16.h>
#include <cmath>

constexpr int H = 256, W = 256;
constexpr int NUMS = 31;                 // (H-16)/8 + 1
constexpr int L = NUMS * NUMS;           // 961
constexpr int B = 2, C = 64;
constexpr float EPS = 1e-5f;

constexpr int NL = 8;                    // query rows per attention block
constexpr int NGROUP = 121;              // ceil(L/NL)
constexpr int LPAD = 968;                // padded l (NGROUP*NL)
constexpr int MPAD = 976;                // padded m (even, >= L, = 2*M2)
constexpr int M2 = 488;                  // m-pairs

typedef __fp16 h2 __attribute__((ext_vector_type(2)));

__device__ inline h2 pk2(float a, float b) {
#if __has_builtin(__builtin_amdgcn_cvt_pkrtz)
    return __builtin_amdgcn_cvt_pkrtz(a, b);
#else
    h2 r; r.x = (__fp16)a; r.y = (__fp16)b; return r;
#endif
}
__device__ inline float h2f(h2 v) { return __builtin_bit_cast(float, v); }
__device__ inline h2 f2h(float v) { return __builtin_bit_cast(h2, v); }

#if __has_builtin(__builtin_amdgcn_fdot2)
#define FDOT2(a, b, c) __builtin_amdgcn_fdot2((a), (b), (c), false)
#else
#define FDOT2(a, b, c) ((c) + (float)(a).x * (float)(b).x + (float)(a).y * (float)(b).y)
#endif

// ---------------------------------------------------------------------------
// Kernel 1: 8x8 cell sums. Patch(16x16,stride8) = 2x2 cells; global = all cells.
// cellsA[b][cell][c] = float4{Sx_bg, Sxx_bg, Sx_all, Sxx_all}; cellsM[b][cell]=Nfg
// ---------------------------------------------------------------------------
__global__ __launch_bounds__(256) void cellsum_kernel(
    const float* __restrict__ x, const float* __restrict__ mask,
    float4* __restrict__ cellsA, float* __restrict__ cellsM)
{
    int cr = blockIdx.x, c = blockIdx.y, b = blockIdx.z;
    int t = threadIdx.x, r = t >> 5, cc = t & 31;
    const float* xp = x + (((size_t)(b * C + c) * H) + cr * 8 + r) * W + cc * 8;
    const float* mp = mask + (((size_t)b * H) + cr * 8 + r) * W + cc * 8;

    float s0 = 0.f, s1 = 0.f, s2 = 0.f, s3 = 0.f, nf = 0.f;
#pragma unroll
    for (int q = 0; q < 2; ++q) {
        float4 xv = ((const float4*)xp)[q];
        float4 mv = ((const float4*)mp)[q];
        float xs[4] = {xv.x, xv.y, xv.z, xv.w};
        float ms[4] = {mv.x, mv.y, mv.z, mv.w};
#pragma unroll
        for (int j = 0; j < 4; ++j) {
            float xx = xs[j], m = ms[j], om = 1.f - m;
            s0 += xx * om; s1 += xx * xx * om;
            s2 += xx;      s3 += xx * xx;
            nf += m;
        }
    }
    // combine row pairs within wave: lanes (i) <-> (i^32) are rows 2w, 2w+1
    s0 += __shfl_xor(s0, 32); s1 += __shfl_xor(s1, 32);
    s2 += __shfl_xor(s2, 32); s3 += __shfl_xor(s3, 32);
    nf += __shfl_xor(nf, 32);

    __shared__ float red[4][32][5];
    int wv = t >> 6;
    if ((t & 63) < 32) {
        red[wv][cc][0] = s0; red[wv][cc][1] = s1; red[wv][cc][2] = s2;
        red[wv][cc][3] = s3; red[wv][cc][4] = nf;
    }
    __syncthreads();
    if (t < 32) {
        float a0 = red[0][t][0] + red[1][t][0] + red[2][t][0] + red[3][t][0];
        float a1 = red[0][t][1] + red[1][t][1] + red[2][t][1] + red[3][t][1];
        float a2 = red[0][t][2] + red[1][t][2] + red[2][t][2] + red[3][t][2];
        float a3 = red[0][t][3] + red[1][t][3] + red[2][t][3] + red[3][t][3];
        float an = red[0][t][4] + red[1][t][4] + red[2][t][4] + red[3][t][4];
        int cell = cr * 32 + t;
        cellsA[((size_t)b * 1024 + cell) * C + c] = make_float4(a0, a1, a2, a3);
        if (c == 0) cellsM[(size_t)b * 1024 + cell] = an;
    }
}

// ---------------------------------------------------------------------------
// Kernel 2: global stats per (b,c) from cells.
// stats[bc*4 + {mu_b, inv_std_b, mu_f, inv_std_f}]
// ---------------------------------------------------------------------------
__global__ __launch_bounds__(256) void stats_kernel(
    const float4* __restrict__ cellsA, const float* __restrict__ cellsM,
    float* __restrict__ stats)
{
    int c = blockIdx.x, b = blockIdx.y, t = threadIdx.x;
    float s0 = 0.f, s1 = 0.f, s2 = 0.f, s3 = 0.f, nf = 0.f;
    for (int e = t; e < 1024; e += 256) {
        float4 v = cellsA[((size_t)b * 1024 + e) * C + c];
        s0 += v.x; s1 += v.y; s2 += v.z; s3 += v.w;
        nf += cellsM[(size_t)b * 1024 + e];
    }
#pragma unroll
    for (int off = 32; off; off >>= 1) {
        s0 += __shfl_xor(s0, off); s1 += __shfl_xor(s1, off);
        s2 += __shfl_xor(s2, off); s3 += __shfl_xor(s3, off);
        nf += __shfl_xor(nf, off);
    }
    __shared__ float red[4][5];
    if ((t & 63) == 0) {
        red[t >> 6][0] = s0; red[t >> 6][1] = s1; red[t >> 6][2] = s2;
        red[t >> 6][3] = s3; red[t >> 6][4] = nf;
    }
    __syncthreads();
    if (t == 0) {
        float a0 = red[0][0] + red[1][0] + red[2][0] + red[3][0];
        float a1 = red[0][1] + red[1][1] + red[2][1] + red[3][1];
        float a2 = red[0][2] + red[1][2] + red[2][2] + red[3][2];
        float a3 = red[0][3] + red[1][3] + red[2][3] + red[3][3];
        float an = red[0][4] + red[1][4] + red[2][4] + red[3][4];
        float numbg = (float)(H * W) - an;
        float mu_b = a0 / (numbg + EPS);
        float var_b = (a1 - 2.f * mu_b * a0 + mu_b * mu_b * numbg) / (numbg + EPS);
        float sxfg = a2 - a0, sxxfg = a3 - a1;
        float mu_f = sxfg / (an + EPS);
        float var_f = (sxxfg - 2.f * mu_f * sxfg + mu_f * mu_f * an) / (an + EPS);
        float* st = stats + ((size_t)b * C + c) * 4;
        st[0] = mu_b; st[1] = 1.f / sqrtf(var_b + EPS);
        st[2] = mu_f; st[3] = 1.f / sqrtf(var_f + EPS);
    }
}

// ---------------------------------------------------------------------------
// Kernel 3: patch finalize from cells. Block = (b, l-quad); lane = c.
// qTT/kTT laid out [b][c][l] (for wave-uniform scalar loads in attention);
// mvh[b][m2][c] = float2{h2(mu1_even,mu1_odd), h2(var1_even,var1_odd)}.
// ---------------------------------------------------------------------------
__global__ __launch_bounds__(256) void patchfinal_kernel(
    const float4* __restrict__ cellsA, const float* __restrict__ cellsM,
    const float* __restrict__ stats,
    const float* __restrict__ qg, const float* __restrict__ qb,
    const float* __restrict__ kg, const float* __restrict__ kb,
    float* __restrict__ qTT, float* __restrict__ kTT, float2* __restrict__ mvh)
{
    int lq = blockIdx.x, b = blockIdx.y;
    int t = threadIdx.x, ls = t >> 6, c = t & 63;
    int l = lq * 4 + ls;

    float mu1 = 0.f, var1 = 0.f, qv = 0.f, kv = 0.f;
    if (l < L) {
        int lh = l / 31, lw = l % 31;
        int e00 = lh * 32 + lw;
        size_t base = (size_t)b * 1024;
        float4 s00 = cellsA[(base + e00) * C + c];
        float4 s01 = cellsA[(base + e00 + 1) * C + c];
        float4 s10 = cellsA[(base + e00 + 32) * C + c];
        float4 s11 = cellsA[(base + e00 + 33) * C + c];
        float sxbg = s00.x + s01.x + s10.x + s11.x;
        float sxxbg = s00.y + s01.y + s10.y + s11.y;
        float sxall = s00.z + s01.z + s10.z + s11.z;
        float nfg = cellsM[base + e00] + cellsM[base + e00 + 1]
                  + cellsM[base + e00 + 32] + cellsM[base + e00 + 33];
        float numbg = 256.f - nfg;
        float rb = 1.f / (numbg + EPS), rf = 1.f / (nfg + EPS);
        const float* st = stats + ((size_t)b * C + c) * 4;
        float mu_b = st[0], isb = st[1], mu_f = st[2], isf = st[3];
        mu1 = sxbg * rb;
        var1 = (sxxbg - 2.f * mu1 * sxbg + mu1 * mu1 * numbg) * rb;
        float mu4 = (sxbg - mu_b * numbg) * isb * rb;
        float sxfg = sxall - sxbg;
        float mu3 = (sxfg - mu_f * nfg) * isf * rf;
        qv = mu3 * qg[c] + qb[c];
        kv = mu4 * kg[c] + kb[c];
    }
    qTT[((size_t)(b * C + c)) * LPAD + l] = qv;
    kTT[((size_t)(b * C + c)) * MPAD + l] = kv;

    __shared__ float smu[4][64], svar[4][64];
    smu[ls][c] = mu1; svar[ls][c] = var1;
    __syncthreads();
    if (t < 128) {
        int p = t >> 6, cc = t & 63;
        h2 mp_ = pk2(smu[2 * p][cc], smu[2 * p + 1][cc]);
        h2 vp_ = pk2(svar[2 * p][cc], svar[2 * p + 1][cc]);
        mvh[((size_t)b * M2 + lq * 2 + p) * C + cc] = make_float2(h2f(mp_), h2f(vp_));
    }
}

// ---------------------------------------------------------------------------
// Kernel 4: fused attention per (b, 8-query group). 512 threads.
// QK: lane=m (coalesced kTT[c][m]), q via wave-uniform scalar loads, max-free
// exp, w packed f16 pairs to LDS. PV: lane=c, per-wave m-slice, v_dot2_f32_f16,
// LDS tree-combine, normalize by row sum.
// ---------------------------------------------------------------------------
__global__ __launch_bounds__(512) void attn_kernel(
    const float* __restrict__ qTT, const float* __restrict__ kTT,
    const float2* __restrict__ mvh, const float* __restrict__ bias_table,
    float* __restrict__ pbT, float* __restrict__ psT)
{
    __shared__ float4 wlds[M2][2];          // f16 w pairs: [m2][8 li]  (15.6KB)
    __shared__ float parts[8][NL][64][2];   // per-wave PV partials     (32KB)
    __shared__ float rsp[8][NL];

    int g = blockIdx.x, b = blockIdx.y;
    int t = threadIdx.x, l0 = g * NL;
    int m0 = t, m1 = t + 512;
    int m1c = m1 < MPAD ? m1 : MPAD - 1;

    int lhs[NL], lws[NL];
#pragma unroll
    for (int li = 0; li < NL; ++li) {
        int l = l0 + li; if (l > L - 1) l = L - 1;
        lhs[li] = l / 31; lws[li] = l % 31;
    }

    float dot0[NL] = {0, 0, 0, 0, 0, 0, 0, 0};
    float dot1[NL] = {0, 0, 0, 0, 0, 0, 0, 0};
    const float* kbase = kTT + (size_t)b * C * MPAD;
    const float* qbase = qTT + (size_t)b * C * LPAD + l0;
#pragma unroll 4
    for (int c = 0; c < C; ++c) {
        float k0 = kbase[(size_t)c * MPAD + m0];
        float k1 = kbase[(size_t)c * MPAD + m1c];
        const float* qp = qbase + (size_t)c * LPAD;   // wave-uniform -> s_load
#pragma unroll
        for (int li = 0; li < NL; ++li) {
            float q = qp[li];
            dot0[li] = fmaf(q, k0, dot0[li]);
            dot1[li] = fmaf(q, k1, dot1[li]);
        }
    }

    float e0[NL], e1[NL];
    float psum[NL] = {0, 0, 0, 0, 0, 0, 0, 0};
    {
        int mh = m0 / 31, mw = m0 - mh * 31;
#pragma unroll
        for (int li = 0; li < NL; ++li) {
            float bias = bias_table[(lhs[li] - mh + 30) * 61 + (lws[li] - mw + 30)];
            e0[li] = __expf(dot0[li] + bias);
            psum[li] += e0[li];
        }
    }
    if (m1 < L) {
        int mh = m1 / 31, mw = m1 - mh * 31;
#pragma unroll
        for (int li = 0; li < NL; ++li) {
            float bias = bias_table[(lhs[li] - mh + 30) * 61 + (lws[li] - mw + 30)];
            e1[li] = __expf(dot1[li] + bias);
            psum[li] += e1[li];
        }
    } else {
#pragma unroll
        for (int li = 0; li < NL; ++li) e1[li] = 0.f;
    }

    // pack (even m, odd m) f16 pairs into LDS
    {
        float n0[NL], n1[NL];
#pragma unroll
        for (int li = 0; li < NL; ++li) {
            n0[li] = __shfl_down(e0[li], 1);
            n1[li] = __shfl_down(e1[li], 1);
        }
        if (!(t & 1)) {
            wlds[m0 >> 1][0] = make_float4(h2f(pk2(e0[0], n0[0])), h2f(pk2(e0[1], n0[1])),
                                           h2f(pk2(e0[2], n0[2])), h2f(pk2(e0[3], n0[3])));
            wlds[m0 >> 1][1] = make_float4(h2f(pk2(e0[4], n0[4])), h2f(pk2(e0[5], n0[5])),
                                           h2f(pk2(e0[6], n0[6])), h2f(pk2(e0[7], n0[7])));
            if (m1 < MPAD) {
                wlds[m1 >> 1][0] = make_float4(h2f(pk2(e1[0], n1[0])), h2f(pk2(e1[1], n1[1])),
                                               h2f(pk2(e1[2], n1[2])), h2f(pk2(e1[3], n1[3])));
                wlds[m1 >> 1][1] = make_float4(h2f(pk2(e1[4], n1[4])), h2f(pk2(e1[5], n1[5])),
                                               h2f(pk2(e1[6], n1[6])), h2f(pk2(e1[7], n1[7])));
            }
        }
    }
#pragma unroll
    for (int li = 0; li < NL; ++li) {
        float v = psum[li];
#pragma unroll
        for (int off = 32; off; off >>= 1) v += __shfl_xor(v, off);
        if ((t & 63) == 0) rsp[t >> 6][li] = v;
    }
    __syncthreads();

    // PV: wave wv covers m2 in [wv*61, wv*61+61)
    int wv = t >> 6, c = t & 63;
    float accb[NL] = {0, 0, 0, 0, 0, 0, 0, 0};
    float accs[NL] = {0, 0, 0, 0, 0, 0, 0, 0};
    const float2* vbase = mvh + (size_t)b * M2 * C + c;
    int mstart = wv * 61;
#pragma unroll 2
    for (int i = 0; i < 61; ++i) {
        int m2 = mstart + i;
        float4 wa = wlds[m2][0];
        float4 wb = wlds[m2][1];
        float2 v = vbase[(size_t)m2 * C];
        h2 vb = f2h(v.x), vs = f2h(v.y);
        accb[0] = FDOT2(f2h(wa.x), vb, accb[0]); accs[0] = FDOT2(f2h(wa.x), vs, accs[0]);
        accb[1] = FDOT2(f2h(wa.y), vb, accb[1]); accs[1] = FDOT2(f2h(wa.y), vs, accs[1]);
        accb[2] = FDOT2(f2h(wa.z), vb, accb[2]); accs[2] = FDOT2(f2h(wa.z), vs, accs[2]);
        accb[3] = FDOT2(f2h(wa.w), vb, accb[3]); accs[3] = FDOT2(f2h(wa.w), vs, accs[3]);
        accb[4] = FDOT2(f2h(wb.x), vb, accb[4]); accs[4] = FDOT2(f2h(wb.x), vs, accs[4]);
        accb[5] = FDOT2(f2h(wb.y), vb, accb[5]); accs[5] = FDOT2(f2h(wb.y), vs, accs[5]);
        accb[6] = FDOT2(f2h(wb.z), vb, accb[6]); accs[6] = FDOT2(f2h(wb.z), vs, accs[6]);
        accb[7] = FDOT2(f2h(wb.w), vb, accb[7]); accs[7] = FDOT2(f2h(wb.w), vs, accs[7]);
    }
#pragma unroll
    for (int li = 0; li < NL; ++li) {
        parts[wv][li][c][0] = accb[li];
        parts[wv][li][c][1] = accs[li];
    }
    __syncthreads();

    int li = t >> 6;   // 8 li x 64 c == 512 threads
    float sb = 0.f, ss = 0.f, rs = 0.f;
#pragma unroll
    for (int w = 0; w < 8; ++w) {
        sb += parts[w][li][c][0];
        ss += parts[w][li][c][1];
        rs += rsp[w][li];
    }
    if (l0 + li < L) {
        float inv = 1.f / rs;
        size_t o = ((size_t)b * L + l0 + li) * C + c;
        pbT[o] = sb * inv;
        psT[o] = ss * inv;
    }
}

// ---------------------------------------------------------------------------
// Kernel 5: fused epilogue (x4 vectorized fold + affines).
// ---------------------------------------------------------------------------
__global__ __launch_bounds__(256) void out_kernel(
    const float* __restrict__ x, const float* __restrict__ mask,
    const float* __restrict__ stats,
    const float* __restrict__ pbT, const float* __restrict__ psT,
    const float* __restrict__ fgg, const float* __restrict__ fgb,
    const float* __restrict__ bgg, const float* __restrict__ bgb,
    float* __restrict__ out)
{
    int idx = blockIdx.x * 256 + threadIdx.x;   // one float4 each
    int w4 = idx & (W / 4 - 1);
    int rest = idx >> 6;
    int h = rest & (H - 1);
    int bc = rest >> 8;
    int c = bc & (C - 1);
    int b = bc >> 6;
    int w = w4 * 4;

    size_t pix = ((size_t)bc * H + h) * W + w;
    float4 xv = *(const float4*)&x[pix];
    float4 mv = *(const float4*)&mask[((size_t)b * H + h) * W + w];

    const float* st = stats + (size_t)bc * 4;
    float mu_f = st[2], isf = st[3];

    int hq = h >> 3, wq = w >> 3;
    int ph0 = hq > 0 ? hq - 1 : 0;
    int ph1 = hq < NUMS ? hq : NUMS - 1;
    int pw0 = wq > 0 ? wq - 1 : 0;
    int pw1 = wq < NUMS ? wq : NUMS - 1;

    float sstd = 0.f, sback = 0.f, cnt = 0.f;
    for (int ph = ph0; ph <= ph1; ++ph)
        for (int pw = pw0; pw <= pw1; ++pw) {
            size_t o = ((size_t)b * L + ph * NUMS + pw) * C + c;
            sstd += psT[o];
            sback += pbT[o];
            cnt += 1.f;
        }
    float rcnt = 1.f / cnt;
    float ga = 1.f + fgg[c], be = fgb[c];
    float gb_ = 1.f + bgg[c], bb = bgb[c];

    float xs[4] = {xv.x, xv.y, xv.z, xv.w};
    float ms_[4] = {mv.x, mv.y, mv.z, mv.w};
    float4 res;
    float* rp = &res.x;
#pragma unroll
    for (int j = 0; j < 4; ++j) {
        float nfg_px = (xs[j] - mu_f) * isf * ms_[j];
        float nf = (nfg_px * sstd + sback) * rcnt;
        rp[j] = (nf * ga + be) * ms_[j] + (xs[j] * gb_ + bb) * (1.f - ms_[j]);
    }
    *(float4*)&out[pix] = res;
}

// ---------------------------------------------------------------------------
extern "C" void kernel_launch(void* const* d_in, const int* in_sizes, int n_in,
                              void* d_out, int out_size, void* d_ws, size_t ws_size,
                              hipStream_t stream)
{
    const float* x    = (const float*)d_in[0];
    const float* mask = (const float*)d_in[1];
    const float* fgg  = (const float*)d_in[2];
    const float* fgb  = (const float*)d_in[3];
    const float* bgg  = (const float*)d_in[4];
    const float* bgb  = (const float*)d_in[5];
    const float* qg   = (const float*)d_in[6];
    const float* qb   = (const float*)d_in[7];
    const float* kg   = (const float*)d_in[8];
    const float* kb   = (const float*)d_in[9];
    const float* bt   = (const float*)d_in[10];
    float* out = (float*)d_out;

    float* ws = (float*)d_ws;
    float4* cellsA = (float4*)ws;                        // B*1024*C float4 = 524288 f
    float* cellsM  = ws + (size_t)B * 1024 * C * 4;      // 2048 f
    float* stats   = cellsM + (size_t)B * 1024;          // 512 f
    float* qTT     = stats + (size_t)B * C * 4;          // B*C*LPAD = 123904 f
    float* kTT     = qTT + (size_t)B * C * LPAD;         // B*C*MPAD = 124928 f
    float2* mvh    = (float2*)(kTT + (size_t)B * C * MPAD); // B*M2*C float2 = 124928 f
    float* pbT     = (float*)mvh + (size_t)B * M2 * C * 2;  // 123008 f
    float* psT     = pbT + (size_t)B * L * C;               // 123008 f

    cellsum_kernel<<<dim3(32, C, B), 256, 0, stream>>>(x, mask, cellsA, cellsM);
    stats_kernel<<<dim3(C, B), 256, 0, stream>>>(cellsA, cellsM, stats);
    patchfinal_kernel<<<dim3(241, B), 256, 0, stream>>>(
        cellsA, cellsM, stats, qg, qb, kg, kb, qTT, kTT, mvh);
    attn_kernel<<<dim3(NGROUP, B), 512, 0, stream>>>(qTT, kTT, mvh, bt, pbT, psT);
    out_kernel<<<(B * C * H * W / 4 + 255) / 256, 256, 0, stream>>>(
        x, mask, stats, pbT, psT, fgg, fgb, bgg, bgb, out);
}

// Round 5
// 69.318 us; speedup vs baseline: 2.4478x; 1.2688x over previous
//
#include <hip/hip_runtime.h>
#include <hip/hip_fp16.h>
#include <cmath>

constexpr int H = 256, W = 256;
constexpr int NUMS = 31;                 // (H-16)/8 + 1
constexpr int L = NUMS * NUMS;           // 961
constexpr int B = 2, C = 64;
constexpr float EPS = 1e-5f;

constexpr int NL = 8;                    // query rows per attention block
constexpr int NGROUP = 121;              // ceil(L/NL)
constexpr int LPAD = 968;                // padded l (NGROUP*NL, 16B-aligned rows)
constexpr int MPAD = 976;                // padded m (even, >= L, = 2*M2)
constexpr int M2 = 488;                  // m-pairs

typedef __fp16 h2 __attribute__((ext_vector_type(2)));

__device__ inline h2 pk2(float a, float b) {
#if __has_builtin(__builtin_amdgcn_cvt_pkrtz)
    return __builtin_amdgcn_cvt_pkrtz(a, b);
#else
    h2 r; r.x = (__fp16)a; r.y = (__fp16)b; return r;
#endif
}
__device__ inline float h2f(h2 v) { return __builtin_bit_cast(float, v); }
__device__ inline h2 f2h(float v) { return __builtin_bit_cast(h2, v); }

#if __has_builtin(__builtin_amdgcn_fdot2)
#define FDOT2(a, b, c) __builtin_amdgcn_fdot2((a), (b), (c), false)
#else
#define FDOT2(a, b, c) ((c) + (float)(a).x * (float)(b).x + (float)(a).y * (float)(b).y)
#endif

// ---------------------------------------------------------------------------
// Kernel 1: 8x8 cell sums. Patch(16x16,stride8) = 2x2 cells; global = all cells.
// cellsA[b][cell][c] = float4{Sx_bg, Sxx_bg, Sx_all, Sxx_all}; cellsM[b][cell]=Nfg
// ---------------------------------------------------------------------------
__global__ __launch_bounds__(256) void cellsum_kernel(
    const float* __restrict__ x, const float* __restrict__ mask,
    float4* __restrict__ cellsA, float* __restrict__ cellsM)
{
    int cr = blockIdx.x, c = blockIdx.y, b = blockIdx.z;
    int t = threadIdx.x, r = t >> 5, cc = t & 31;
    const float* xp = x + (((size_t)(b * C + c) * H) + cr * 8 + r) * W + cc * 8;
    const float* mp = mask + (((size_t)b * H) + cr * 8 + r) * W + cc * 8;

    float s0 = 0.f, s1 = 0.f, s2 = 0.f, s3 = 0.f, nf = 0.f;
#pragma unroll
    for (int q = 0; q < 2; ++q) {
        float4 xv = ((const float4*)xp)[q];
        float4 mv = ((const float4*)mp)[q];
        float xs[4] = {xv.x, xv.y, xv.z, xv.w};
        float ms[4] = {mv.x, mv.y, mv.z, mv.w};
#pragma unroll
        for (int j = 0; j < 4; ++j) {
            float xx = xs[j], m = ms[j], om = 1.f - m;
            s0 += xx * om; s1 += xx * xx * om;
            s2 += xx;      s3 += xx * xx;
            nf += m;
        }
    }
    // combine row pairs within wave: lanes (i) <-> (i^32) are rows 2w, 2w+1
    s0 += __shfl_xor(s0, 32); s1 += __shfl_xor(s1, 32);
    s2 += __shfl_xor(s2, 32); s3 += __shfl_xor(s3, 32);
    nf += __shfl_xor(nf, 32);

    __shared__ float red[4][32][5];
    int wv = t >> 6;
    if ((t & 63) < 32) {
        red[wv][cc][0] = s0; red[wv][cc][1] = s1; red[wv][cc][2] = s2;
        red[wv][cc][3] = s3; red[wv][cc][4] = nf;
    }
    __syncthreads();
    if (t < 32) {
        float a0 = red[0][t][0] + red[1][t][0] + red[2][t][0] + red[3][t][0];
        float a1 = red[0][t][1] + red[1][t][1] + red[2][t][1] + red[3][t][1];
        float a2 = red[0][t][2] + red[1][t][2] + red[2][t][2] + red[3][t][2];
        float a3 = red[0][t][3] + red[1][t][3] + red[2][t][3] + red[3][t][3];
        float an = red[0][t][4] + red[1][t][4] + red[2][t][4] + red[3][t][4];
        int cell = cr * 32 + t;
        cellsA[((size_t)b * 1024 + cell) * C + c] = make_float4(a0, a1, a2, a3);
        if (c == 0) cellsM[(size_t)b * 1024 + cell] = an;
    }
}

// ---------------------------------------------------------------------------
// Kernel 2: global stats per (b,c) from cells.
// stats[bc*4 + {mu_b, inv_std_b, mu_f, inv_std_f}]
// ---------------------------------------------------------------------------
__global__ __launch_bounds__(256) void stats_kernel(
    const float4* __restrict__ cellsA, const float* __restrict__ cellsM,
    float* __restrict__ stats)
{
    int c = blockIdx.x, b = blockIdx.y, t = threadIdx.x;
    float s0 = 0.f, s1 = 0.f, s2 = 0.f, s3 = 0.f, nf = 0.f;
    for (int e = t; e < 1024; e += 256) {
        float4 v = cellsA[((size_t)b * 1024 + e) * C + c];
        s0 += v.x; s1 += v.y; s2 += v.z; s3 += v.w;
        nf += cellsM[(size_t)b * 1024 + e];
    }
#pragma unroll
    for (int off = 32; off; off >>= 1) {
        s0 += __shfl_xor(s0, off); s1 += __shfl_xor(s1, off);
        s2 += __shfl_xor(s2, off); s3 += __shfl_xor(s3, off);
        nf += __shfl_xor(nf, off);
    }
    __shared__ float red[4][5];
    if ((t & 63) == 0) {
        red[t >> 6][0] = s0; red[t >> 6][1] = s1; red[t >> 6][2] = s2;
        red[t >> 6][3] = s3; red[t >> 6][4] = nf;
    }
    __syncthreads();
    if (t == 0) {
        float a0 = red[0][0] + red[1][0] + red[2][0] + red[3][0];
        float a1 = red[0][1] + red[1][1] + red[2][1] + red[3][1];
        float a2 = red[0][2] + red[1][2] + red[2][2] + red[3][2];
        float a3 = red[0][3] + red[1][3] + red[2][3] + red[3][3];
        float an = red[0][4] + red[1][4] + red[2][4] + red[3][4];
        float numbg = (float)(H * W) - an;
        float mu_b = a0 / (numbg + EPS);
        float var_b = (a1 - 2.f * mu_b * a0 + mu_b * mu_b * numbg) / (numbg + EPS);
        float sxfg = a2 - a0, sxxfg = a3 - a1;
        float mu_f = sxfg / (an + EPS);
        float var_f = (sxxfg - 2.f * mu_f * sxfg + mu_f * mu_f * an) / (an + EPS);
        float* st = stats + ((size_t)b * C + c) * 4;
        st[0] = mu_b; st[1] = 1.f / sqrtf(var_b + EPS);
        st[2] = mu_f; st[3] = 1.f / sqrtf(var_f + EPS);
    }
}

// ---------------------------------------------------------------------------
// Kernel 3: patch finalize from cells. Block = (b, l-quad); lane = c.
// qTT/kTT laid out [b][c][l] (for wave-uniform scalar loads in attention);
// mvh[b][m2][c] = float2{h2(mu1_even,mu1_odd), h2(var1_even,var1_odd)}.
// ---------------------------------------------------------------------------
__global__ __launch_bounds__(256) void patchfinal_kernel(
    const float4* __restrict__ cellsA, const float* __restrict__ cellsM,
    const float* __restrict__ stats,
    const float* __restrict__ qg, const float* __restrict__ qb,
    const float* __restrict__ kg, const float* __restrict__ kb,
    float* __restrict__ qTT, float* __restrict__ kTT, float2* __restrict__ mvh)
{
    int lq = blockIdx.x, b = blockIdx.y;
    int t = threadIdx.x, ls = t >> 6, c = t & 63;
    int l = lq * 4 + ls;

    float mu1 = 0.f, var1 = 0.f, qv = 0.f, kv = 0.f;
    if (l < L) {
        int lh = l / 31, lw = l % 31;
        int e00 = lh * 32 + lw;
        size_t base = (size_t)b * 1024;
        float4 s00 = cellsA[(base + e00) * C + c];
        float4 s01 = cellsA[(base + e00 + 1) * C + c];
        float4 s10 = cellsA[(base + e00 + 32) * C + c];
        float4 s11 = cellsA[(base + e00 + 33) * C + c];
        float sxbg = s00.x + s01.x + s10.x + s11.x;
        float sxxbg = s00.y + s01.y + s10.y + s11.y;
        float sxall = s00.z + s01.z + s10.z + s11.z;
        float nfg = cellsM[base + e00] + cellsM[base + e00 + 1]
                  + cellsM[base + e00 + 32] + cellsM[base + e00 + 33];
        float numbg = 256.f - nfg;
        float rb = 1.f / (numbg + EPS), rf = 1.f / (nfg + EPS);
        const float* st = stats + ((size_t)b * C + c) * 4;
        float mu_b = st[0], isb = st[1], mu_f = st[2], isf = st[3];
        mu1 = sxbg * rb;
        var1 = (sxxbg - 2.f * mu1 * sxbg + mu1 * mu1 * numbg) * rb;
        float mu4 = (sxbg - mu_b * numbg) * isb * rb;
        float sxfg = sxall - sxbg;
        float mu3 = (sxfg - mu_f * nfg) * isf * rf;
        qv = mu3 * qg[c] + qb[c];
        kv = mu4 * kg[c] + kb[c];
    }
    qTT[((size_t)(b * C + c)) * LPAD + l] = qv;
    kTT[((size_t)(b * C + c)) * MPAD + l] = kv;

    __shared__ float smu[4][64], svar[4][64];
    smu[ls][c] = mu1; svar[ls][c] = var1;
    __syncthreads();
    if (t < 128) {
        int p = t >> 6, cc = t & 63;
        h2 mp_ = pk2(smu[2 * p][cc], smu[2 * p + 1][cc]);
        h2 vp_ = pk2(svar[2 * p][cc], svar[2 * p + 1][cc]);
        mvh[((size_t)b * M2 + lq * 2 + p) * C + cc] = make_float2(h2f(mp_), h2f(vp_));
    }
}

// ---------------------------------------------------------------------------
// Kernel 4: fused attention per (b, 8-query group). 512 threads.
// QK: lane=m (coalesced kTT[c][m]), q via wave-uniform scalar loads, max-free
// exp, w packed f16 pairs to LDS. PV: lane=c, per-wave m-slice, v_dot2_f32_f16,
// LDS tree-combine, normalize by row sum. Output TRANSPOSED [b][c][l].
// ---------------------------------------------------------------------------
__global__ __launch_bounds__(512) void attn_kernel(
    const float* __restrict__ qTT, const float* __restrict__ kTT,
    const float2* __restrict__ mvh, const float* __restrict__ bias_table,
    float* __restrict__ pbTc, float* __restrict__ psTc)
{
    __shared__ float4 wlds[M2][2];          // f16 w pairs: [m2][8 li]  (15.6KB)
    __shared__ float parts[8][NL][65][2];   // per-wave PV partials, pad 65 (32.5KB)
    __shared__ float rsp[8][NL];

    int g = blockIdx.x, b = blockIdx.y;
    int t = threadIdx.x, l0 = g * NL;
    int m0 = t, m1 = t + 512;
    int m1c = m1 < MPAD ? m1 : MPAD - 1;

    int lhs[NL], lws[NL];
#pragma unroll
    for (int li = 0; li < NL; ++li) {
        int l = l0 + li; if (l > L - 1) l = L - 1;
        lhs[li] = l / 31; lws[li] = l % 31;
    }

    float dot0[NL] = {0, 0, 0, 0, 0, 0, 0, 0};
    float dot1[NL] = {0, 0, 0, 0, 0, 0, 0, 0};
    const float* kbase = kTT + (size_t)b * C * MPAD;
    const float* qbase = qTT + (size_t)b * C * LPAD + l0;
#pragma unroll 4
    for (int c = 0; c < C; ++c) {
        float k0 = kbase[(size_t)c * MPAD + m0];
        float k1 = kbase[(size_t)c * MPAD + m1c];
        const float* qp = qbase + (size_t)c * LPAD;   // wave-uniform -> s_load
#pragma unroll
        for (int li = 0; li < NL; ++li) {
            float q = qp[li];
            dot0[li] = fmaf(q, k0, dot0[li]);
            dot1[li] = fmaf(q, k1, dot1[li]);
        }
    }

    float e0[NL], e1[NL];
    float psum[NL] = {0, 0, 0, 0, 0, 0, 0, 0};
    {
        int mh = m0 / 31, mw = m0 - mh * 31;
#pragma unroll
        for (int li = 0; li < NL; ++li) {
            float bias = bias_table[(lhs[li] - mh + 30) * 61 + (lws[li] - mw + 30)];
            e0[li] = __expf(dot0[li] + bias);
            psum[li] += e0[li];
        }
    }
    if (m1 < L) {
        int mh = m1 / 31, mw = m1 - mh * 31;
#pragma unroll
        for (int li = 0; li < NL; ++li) {
            float bias = bias_table[(lhs[li] - mh + 30) * 61 + (lws[li] - mw + 30)];
            e1[li] = __expf(dot1[li] + bias);
            psum[li] += e1[li];
        }
    } else {
#pragma unroll
        for (int li = 0; li < NL; ++li) e1[li] = 0.f;
    }

    // pack (even m, odd m) f16 pairs into LDS
    {
        float n0[NL], n1[NL];
#pragma unroll
        for (int li = 0; li < NL; ++li) {
            n0[li] = __shfl_down(e0[li], 1);
            n1[li] = __shfl_down(e1[li], 1);
        }
        if (!(t & 1)) {
            wlds[m0 >> 1][0] = make_float4(h2f(pk2(e0[0], n0[0])), h2f(pk2(e0[1], n0[1])),
                                           h2f(pk2(e0[2], n0[2])), h2f(pk2(e0[3], n0[3])));
            wlds[m0 >> 1][1] = make_float4(h2f(pk2(e0[4], n0[4])), h2f(pk2(e0[5], n0[5])),
                                           h2f(pk2(e0[6], n0[6])), h2f(pk2(e0[7], n0[7])));
            if (m1 < MPAD) {
                wlds[m1 >> 1][0] = make_float4(h2f(pk2(e1[0], n1[0])), h2f(pk2(e1[1], n1[1])),
                                               h2f(pk2(e1[2], n1[2])), h2f(pk2(e1[3], n1[3])));
                wlds[m1 >> 1][1] = make_float4(h2f(pk2(e1[4], n1[4])), h2f(pk2(e1[5], n1[5])),
                                               h2f(pk2(e1[6], n1[6])), h2f(pk2(e1[7], n1[7])));
            }
        }
    }
#pragma unroll
    for (int li = 0; li < NL; ++li) {
        float v = psum[li];
#pragma unroll
        for (int off = 32; off; off >>= 1) v += __shfl_xor(v, off);
        if ((t & 63) == 0) rsp[t >> 6][li] = v;
    }
    __syncthreads();

    // PV: wave wv covers m2 in [wv*61, wv*61+61)
    int wv = t >> 6, c = t & 63;
    float accb[NL] = {0, 0, 0, 0, 0, 0, 0, 0};
    float accs[NL] = {0, 0, 0, 0, 0, 0, 0, 0};
    const float2* vbase = mvh + (size_t)b * M2 * C + c;
    int mstart = wv * 61;
#pragma unroll 2
    for (int i = 0; i < 61; ++i) {
        int m2 = mstart + i;
        float4 wa = wlds[m2][0];
        float4 wb = wlds[m2][1];
        float2 v = vbase[(size_t)m2 * C];
        h2 vb = f2h(v.x), vs = f2h(v.y);
        accb[0] = FDOT2(f2h(wa.x), vb, accb[0]); accs[0] = FDOT2(f2h(wa.x), vs, accs[0]);
        accb[1] = FDOT2(f2h(wa.y), vb, accb[1]); accs[1] = FDOT2(f2h(wa.y), vs, accs[1]);
        accb[2] = FDOT2(f2h(wa.z), vb, accb[2]); accs[2] = FDOT2(f2h(wa.z), vs, accs[2]);
        accb[3] = FDOT2(f2h(wa.w), vb, accb[3]); accs[3] = FDOT2(f2h(wa.w), vs, accs[3]);
        accb[4] = FDOT2(f2h(wb.x), vb, accb[4]); accs[4] = FDOT2(f2h(wb.x), vs, accs[4]);
        accb[5] = FDOT2(f2h(wb.y), vb, accb[5]); accs[5] = FDOT2(f2h(wb.y), vs, accs[5]);
        accb[6] = FDOT2(f2h(wb.z), vb, accb[6]); accs[6] = FDOT2(f2h(wb.z), vs, accs[6]);
        accb[7] = FDOT2(f2h(wb.w), vb, accb[7]); accs[7] = FDOT2(f2h(wb.w), vs, accs[7]);
    }
#pragma unroll
    for (int li = 0; li < NL; ++li) {
        parts[wv][li][c][0] = accb[li];
        parts[wv][li][c][1] = accs[li];
    }
    __syncthreads();

    // final: li fastest (coalesced-ish 32B runs along l), write [b][c][l]
    {
        int li = t & 7, co = t >> 3;       // 512 threads = 8 li x 64 c
        float sb = 0.f, ss = 0.f, rs = 0.f;
#pragma unroll
        for (int w = 0; w < 8; ++w) {
            sb += parts[w][li][co][0];
            ss += parts[w][li][co][1];
            rs += rsp[w][li];
        }
        if (l0 + li < L) {
            float inv = 1.f / rs;
            size_t o = ((size_t)(b * C + co)) * LPAD + l0 + li;
            pbTc[o] = sb * inv;
            psTc[o] = ss * inv;
        }
    }
}

// ---------------------------------------------------------------------------
// Kernel 5: fused epilogue (x4 vectorized fold + affines). Transposed
// pbTc/psTc [b][c][LPAD]: a wave's fold gathers span ~33 consecutive floats
// per patch-row -> ~5 cache lines per gather instruction.
// ---------------------------------------------------------------------------
__global__ __launch_bounds__(256) void out_kernel(
    const float* __restrict__ x, const float* __restrict__ mask,
    const float* __restrict__ stats,
    const float* __restrict__ pbTc, const float* __restrict__ psTc,
    const float* __restrict__ fgg, const float* __restrict__ fgb,
    const float* __restrict__ bgg, const float* __restrict__ bgb,
    float* __restrict__ out)
{
    int idx = blockIdx.x * 256 + threadIdx.x;   // one float4 each
    int w4 = idx & (W / 4 - 1);
    int rest = idx >> 6;
    int h = rest & (H - 1);
    int bc = rest >> 8;
    int c = bc & (C - 1);
    int b = bc >> 6;
    int w = w4 * 4;

    size_t pix = ((size_t)bc * H + h) * W + w;
    float4 xv = *(const float4*)&x[pix];
    float4 mv = *(const float4*)&mask[((size_t)b * H + h) * W + w];

    const float* st = stats + (size_t)bc * 4;
    float mu_f = st[2], isf = st[3];

    int hq = h >> 3, wq = w >> 3;
    int ph0 = hq > 0 ? hq - 1 : 0;
    int ph1 = hq < NUMS ? hq : NUMS - 1;
    int pw0 = wq > 0 ? wq - 1 : 0;
    int pw1 = wq < NUMS ? wq : NUMS - 1;

    const float* pbc = pbTc + (size_t)bc * LPAD;
    const float* psc = psTc + (size_t)bc * LPAD;

    float sstd = 0.f, sback = 0.f;
    for (int ph = ph0; ph <= ph1; ++ph) {
        int base = ph * 31;
        for (int pw = pw0; pw <= pw1; ++pw) {
            sstd += psc[base + pw];
            sback += pbc[base + pw];
        }
    }
    float rcnt = 1.f / (float)((ph1 - ph0 + 1) * (pw1 - pw0 + 1));
    float ga = 1.f + fgg[c], be = fgb[c];
    float gb_ = 1.f + bgg[c], bb = bgb[c];

    float xs[4] = {xv.x, xv.y, xv.z, xv.w};
    float ms_[4] = {mv.x, mv.y, mv.z, mv.w};
    float4 res;
    float* rp = &res.x;
#pragma unroll
    for (int j = 0; j < 4; ++j) {
        float nfg_px = (xs[j] - mu_f) * isf * ms_[j];
        float nf = (nfg_px * sstd + sback) * rcnt;
        rp[j] = (nf * ga + be) * ms_[j] + (xs[j] * gb_ + bb) * (1.f - ms_[j]);
    }
    *(float4*)&out[pix] = res;
}

// ---------------------------------------------------------------------------
extern "C" void kernel_launch(void* const* d_in, const int* in_sizes, int n_in,
                              void* d_out, int out_size, void* d_ws, size_t ws_size,
                              hipStream_t stream)
{
    const float* x    = (const float*)d_in[0];
    const float* mask = (const float*)d_in[1];
    const float* fgg  = (const float*)d_in[2];
    const float* fgb  = (const float*)d_in[3];
    const float* bgg  = (const float*)d_in[4];
    const float* bgb  = (const float*)d_in[5];
    const float* qg   = (const float*)d_in[6];
    const float* qb   = (const float*)d_in[7];
    const float* kg   = (const float*)d_in[8];
    const float* kb   = (const float*)d_in[9];
    const float* bt   = (const float*)d_in[10];
    float* out = (float*)d_out;

    float* ws = (float*)d_ws;
    float4* cellsA = (float4*)ws;                        // B*1024*C float4
    float* cellsM  = ws + (size_t)B * 1024 * C * 4;      // 2048 f
    float* stats   = cellsM + (size_t)B * 1024;          // 512 f
    float* qTT     = stats + (size_t)B * C * 4;          // B*C*LPAD
    float* kTT     = qTT + (size_t)B * C * LPAD;         // B*C*MPAD
    float2* mvh    = (float2*)(kTT + (size_t)B * C * MPAD); // B*M2*C float2
    float* pbTc    = (float*)mvh + (size_t)B * M2 * C * 2;  // B*C*LPAD
    float* psTc    = pbTc + (size_t)B * C * LPAD;           // B*C*LPAD

    cellsum_kernel<<<dim3(32, C, B), 256, 0, stream>>>(x, mask, cellsA, cellsM);
    stats_kernel<<<dim3(C, B), 256, 0, stream>>>(cellsA, cellsM, stats);
    patchfinal_kernel<<<dim3(241, B), 256, 0, stream>>>(
        cellsA, cellsM, stats, qg, qb, kg, kb, qTT, kTT, mvh);
    attn_kernel<<<dim3(NGROUP, B), 512, 0, stream>>>(qTT, kTT, mvh, bt, pbTc, psTc);
    out_kernel<<<(B * C * H * W / 4 + 255) / 256, 256, 0, stream>>>(
        x, mask, stats, pbTc, psTc, fgg, fgb, bgg, bgb, out);
}

// Round 6
// 63.467 us; speedup vs baseline: 2.6735x; 1.0922x over previous
//
#include <hip/hip_runtime.h>
#include <hip/hip_fp16.h>
#include <cmath>

constexpr int H = 256, W = 256;
constexpr int NUMS = 31;                 // (H-16)/8 + 1
constexpr int L = NUMS * NUMS;           // 961
constexpr int B = 2, C = 64;
constexpr float EPS = 1e-5f;

constexpr int NL = 4;                    // query rows per attention block
constexpr int NGROUP = 241;              // ceil(L/NL)
constexpr int LPAD = 968;                // padded l (>= NGROUP*NL, 16B-aligned rows)
constexpr int MPAD = 976;                // padded m (even, >= L, = 2*M2)
constexpr int M2 = 488;                  // m-pairs

typedef __fp16 h2 __attribute__((ext_vector_type(2)));

__device__ inline h2 pk2(float a, float b) {
#if __has_builtin(__builtin_amdgcn_cvt_pkrtz)
    return __builtin_amdgcn_cvt_pkrtz(a, b);
#else
    h2 r; r.x = (__fp16)a; r.y = (__fp16)b; return r;
#endif
}
__device__ inline float h2f(h2 v) { return __builtin_bit_cast(float, v); }
__device__ inline h2 f2h(float v) { return __builtin_bit_cast(h2, v); }

#if __has_builtin(__builtin_amdgcn_fdot2)
#define FDOT2(a, b, c) __builtin_amdgcn_fdot2((a), (b), (c), false)
#else
#define FDOT2(a, b, c) ((c) + (float)(a).x * (float)(b).x + (float)(a).y * (float)(b).y)
#endif

// ---------------------------------------------------------------------------
// Kernel 1: 8x8 cell sums. Patch(16x16,stride8) = 2x2 cells; global = all cells.
// ---------------------------------------------------------------------------
__global__ __launch_bounds__(256) void cellsum_kernel(
    const float* __restrict__ x, const float* __restrict__ mask,
    float4* __restrict__ cellsA, float* __restrict__ cellsM)
{
    int cr = blockIdx.x, c = blockIdx.y, b = blockIdx.z;
    int t = threadIdx.x, r = t >> 5, cc = t & 31;
    const float* xp = x + (((size_t)(b * C + c) * H) + cr * 8 + r) * W + cc * 8;
    const float* mp = mask + (((size_t)b * H) + cr * 8 + r) * W + cc * 8;

    float s0 = 0.f, s1 = 0.f, s2 = 0.f, s3 = 0.f, nf = 0.f;
#pragma unroll
    for (int q = 0; q < 2; ++q) {
        float4 xv = ((const float4*)xp)[q];
        float4 mv = ((const float4*)mp)[q];
        float xs[4] = {xv.x, xv.y, xv.z, xv.w};
        float ms[4] = {mv.x, mv.y, mv.z, mv.w};
#pragma unroll
        for (int j = 0; j < 4; ++j) {
            float xx = xs[j], m = ms[j], om = 1.f - m;
            s0 += xx * om; s1 += xx * xx * om;
            s2 += xx;      s3 += xx * xx;
            nf += m;
        }
    }
    s0 += __shfl_xor(s0, 32); s1 += __shfl_xor(s1, 32);
    s2 += __shfl_xor(s2, 32); s3 += __shfl_xor(s3, 32);
    nf += __shfl_xor(nf, 32);

    __shared__ float red[4][32][5];
    int wv = t >> 6;
    if ((t & 63) < 32) {
        red[wv][cc][0] = s0; red[wv][cc][1] = s1; red[wv][cc][2] = s2;
        red[wv][cc][3] = s3; red[wv][cc][4] = nf;
    }
    __syncthreads();
    if (t < 32) {
        float a0 = red[0][t][0] + red[1][t][0] + red[2][t][0] + red[3][t][0];
        float a1 = red[0][t][1] + red[1][t][1] + red[2][t][1] + red[3][t][1];
        float a2 = red[0][t][2] + red[1][t][2] + red[2][t][2] + red[3][t][2];
        float a3 = red[0][t][3] + red[1][t][3] + red[2][t][3] + red[3][t][3];
        float an = red[0][t][4] + red[1][t][4] + red[2][t][4] + red[3][t][4];
        int cell = cr * 32 + t;
        cellsA[((size_t)b * 1024 + cell) * C + c] = make_float4(a0, a1, a2, a3);
        if (c == 0) cellsM[(size_t)b * 1024 + cell] = an;
    }
}

// ---------------------------------------------------------------------------
// Kernel 2: global stats per (b,c) from cells.
// ---------------------------------------------------------------------------
__global__ __launch_bounds__(256) void stats_kernel(
    const float4* __restrict__ cellsA, const float* __restrict__ cellsM,
    float* __restrict__ stats)
{
    int c = blockIdx.x, b = blockIdx.y, t = threadIdx.x;
    float s0 = 0.f, s1 = 0.f, s2 = 0.f, s3 = 0.f, nf = 0.f;
    for (int e = t; e < 1024; e += 256) {
        float4 v = cellsA[((size_t)b * 1024 + e) * C + c];
        s0 += v.x; s1 += v.y; s2 += v.z; s3 += v.w;
        nf += cellsM[(size_t)b * 1024 + e];
    }
#pragma unroll
    for (int off = 32; off; off >>= 1) {
        s0 += __shfl_xor(s0, off); s1 += __shfl_xor(s1, off);
        s2 += __shfl_xor(s2, off); s3 += __shfl_xor(s3, off);
        nf += __shfl_xor(nf, off);
    }
    __shared__ float red[4][5];
    if ((t & 63) == 0) {
        red[t >> 6][0] = s0; red[t >> 6][1] = s1; red[t >> 6][2] = s2;
        red[t >> 6][3] = s3; red[t >> 6][4] = nf;
    }
    __syncthreads();
    if (t == 0) {
        float a0 = red[0][0] + red[1][0] + red[2][0] + red[3][0];
        float a1 = red[0][1] + red[1][1] + red[2][1] + red[3][1];
        float a2 = red[0][2] + red[1][2] + red[2][2] + red[3][2];
        float a3 = red[0][3] + red[1][3] + red[2][3] + red[3][3];
        float an = red[0][4] + red[1][4] + red[2][4] + red[3][4];
        float numbg = (float)(H * W) - an;
        float mu_b = a0 / (numbg + EPS);
        float var_b = (a1 - 2.f * mu_b * a0 + mu_b * mu_b * numbg) / (numbg + EPS);
        float sxfg = a2 - a0, sxxfg = a3 - a1;
        float mu_f = sxfg / (an + EPS);
        float var_f = (sxxfg - 2.f * mu_f * sxfg + mu_f * mu_f * an) / (an + EPS);
        float* st = stats + ((size_t)b * C + c) * 4;
        st[0] = mu_b; st[1] = 1.f / sqrtf(var_b + EPS);
        st[2] = mu_f; st[3] = 1.f / sqrtf(var_f + EPS);
    }
}

// ---------------------------------------------------------------------------
// Kernel 3: patch finalize from cells.
// ---------------------------------------------------------------------------
__global__ __launch_bounds__(256) void patchfinal_kernel(
    const float4* __restrict__ cellsA, const float* __restrict__ cellsM,
    const float* __restrict__ stats,
    const float* __restrict__ qg, const float* __restrict__ qb,
    const float* __restrict__ kg, const float* __restrict__ kb,
    float* __restrict__ qTT, float* __restrict__ kTT, float2* __restrict__ mvh)
{
    int lq = blockIdx.x, b = blockIdx.y;
    int t = threadIdx.x, ls = t >> 6, c = t & 63;
    int l = lq * 4 + ls;

    float mu1 = 0.f, var1 = 0.f, qv = 0.f, kv = 0.f;
    if (l < L) {
        int lh = l / 31, lw = l % 31;
        int e00 = lh * 32 + lw;
        size_t base = (size_t)b * 1024;
        float4 s00 = cellsA[(base + e00) * C + c];
        float4 s01 = cellsA[(base + e00 + 1) * C + c];
        float4 s10 = cellsA[(base + e00 + 32) * C + c];
        float4 s11 = cellsA[(base + e00 + 33) * C + c];
        float sxbg = s00.x + s01.x + s10.x + s11.x;
        float sxxbg = s00.y + s01.y + s10.y + s11.y;
        float sxall = s00.z + s01.z + s10.z + s11.z;
        float nfg = cellsM[base + e00] + cellsM[base + e00 + 1]
                  + cellsM[base + e00 + 32] + cellsM[base + e00 + 33];
        float numbg = 256.f - nfg;
        float rb = 1.f / (numbg + EPS), rf = 1.f / (nfg + EPS);
        const float* st = stats + ((size_t)b * C + c) * 4;
        float mu_b = st[0], isb = st[1], mu_f = st[2], isf = st[3];
        mu1 = sxbg * rb;
        var1 = (sxxbg - 2.f * mu1 * sxbg + mu1 * mu1 * numbg) * rb;
        float mu4 = (sxbg - mu_b * numbg) * isb * rb;
        float sxfg = sxall - sxbg;
        float mu3 = (sxfg - mu_f * nfg) * isf * rf;
        qv = mu3 * qg[c] + qb[c];
        kv = mu4 * kg[c] + kb[c];
    }
    qTT[((size_t)(b * C + c)) * LPAD + l] = qv;
    kTT[((size_t)(b * C + c)) * MPAD + l] = kv;

    __shared__ float smu[4][64], svar[4][64];
    smu[ls][c] = mu1; svar[ls][c] = var1;
    __syncthreads();
    if (t < 128) {
        int p = t >> 6, cc = t & 63;
        h2 mp_ = pk2(smu[2 * p][cc], smu[2 * p + 1][cc]);
        h2 vp_ = pk2(svar[2 * p][cc], svar[2 * p + 1][cc]);
        mvh[((size_t)b * M2 + lq * 2 + p) * C + cc] = make_float2(h2f(mp_), h2f(vp_));
    }
}

// ---------------------------------------------------------------------------
// Kernel 4: fused attention per (b, 4-query group). 256 threads (4 waves).
// QK: lane=m over 4 m-chunks, q via wave-uniform scalar loads, max-free exp,
// w packed as f16 pairs -> one float4 per m2 in LDS.
// PV: lane = (mgrp 4) x (ci 16); each ds_read_b128 fetches 4 DISTINCT m2
// (64B/instr vs 16B broadcast); mgrp-reduce via 2 shfl_xor at the end.
// Output transposed [b][c][LPAD].
// ---------------------------------------------------------------------------
__global__ __launch_bounds__(256) void attn_kernel(
    const float* __restrict__ qTT, const float* __restrict__ kTT,
    const float2* __restrict__ mvh, const float* __restrict__ bias_table,
    float* __restrict__ pbTc, float* __restrict__ psTc)
{
    __shared__ float4 wlds[M2];            // 7.8 KB: [m2] = 4 li x h2(m even, m odd)
    __shared__ float parts[4][NL][65][2];  // 8.3 KB
    __shared__ float rsp[4][NL];

    int g = blockIdx.x, b = blockIdx.y;
    int t = threadIdx.x, l0 = g * NL;

    int lhs[NL], lws[NL];
#pragma unroll
    for (int li = 0; li < NL; ++li) {
        int l = l0 + li; if (l > L - 1) l = L - 1;
        lhs[li] = l / 31; lws[li] = l % 31;
    }

    int mm[4] = {t, t + 256, t + 512, t + 768};
    int m3c = mm[3] < MPAD ? mm[3] : MPAD - 1;

    float dot[4][NL];
#pragma unroll
    for (int j = 0; j < 4; ++j)
#pragma unroll
        for (int li = 0; li < NL; ++li) dot[j][li] = 0.f;

    const float* kbase = kTT + (size_t)b * C * MPAD;
    const float* qbase = qTT + (size_t)b * C * LPAD + l0;
#pragma unroll 2
    for (int c = 0; c < C; ++c) {
        float k0 = kbase[(size_t)c * MPAD + mm[0]];
        float k1 = kbase[(size_t)c * MPAD + mm[1]];
        float k2 = kbase[(size_t)c * MPAD + mm[2]];
        float k3 = kbase[(size_t)c * MPAD + m3c];
        const float* qp = qbase + (size_t)c * LPAD;   // wave-uniform -> s_load
#pragma unroll
        for (int li = 0; li < NL; ++li) {
            float q = qp[li];
            dot[0][li] = fmaf(q, k0, dot[0][li]);
            dot[1][li] = fmaf(q, k1, dot[1][li]);
            dot[2][li] = fmaf(q, k2, dot[2][li]);
            dot[3][li] = fmaf(q, k3, dot[3][li]);
        }
    }

    float e[4][NL];
    float psum[NL] = {0.f, 0.f, 0.f, 0.f};
#pragma unroll
    for (int j = 0; j < 4; ++j) {
        int m = mm[j];
        if (m < L) {
            int mh = m / 31, mw = m - (m / 31) * 31;
#pragma unroll
            for (int li = 0; li < NL; ++li) {
                float bias = bias_table[(lhs[li] - mh + 30) * 61 + (lws[li] - mw + 30)];
                e[j][li] = __expf(dot[j][li] + bias);
                psum[li] += e[j][li];
            }
        } else {
#pragma unroll
            for (int li = 0; li < NL; ++li) e[j][li] = 0.f;
        }
    }

    // pack (even m, odd m) f16 pairs into LDS: one float4 per m2
#pragma unroll
    for (int j = 0; j < 4; ++j) {
        float n0 = __shfl_down(e[j][0], 1);
        float n1 = __shfl_down(e[j][1], 1);
        float n2 = __shfl_down(e[j][2], 1);
        float n3 = __shfl_down(e[j][3], 1);
        if (!(t & 1) && mm[j] < MPAD) {
            wlds[mm[j] >> 1] = make_float4(h2f(pk2(e[j][0], n0)), h2f(pk2(e[j][1], n1)),
                                           h2f(pk2(e[j][2], n2)), h2f(pk2(e[j][3], n3)));
        }
    }
#pragma unroll
    for (int li = 0; li < NL; ++li) {
        float v = psum[li];
#pragma unroll
        for (int off = 32; off; off >>= 1) v += __shfl_xor(v, off);
        if ((t & 63) == 0) rsp[t >> 6][li] = v;
    }
    __syncthreads();

    // PV: lane = mg*16 + ci. m2 = i*16 + wv*4 + mg.
    int wv = t >> 6, lane = t & 63;
    int mg = lane >> 4, ci = lane & 15;
    float accb[NL][4], accs[NL][4];
#pragma unroll
    for (int li = 0; li < NL; ++li)
#pragma unroll
        for (int cs = 0; cs < 4; ++cs) { accb[li][cs] = 0.f; accs[li][cs] = 0.f; }

    const float2* vbase = mvh + (size_t)b * M2 * C;
    int moff = (wv << 2) + mg;
    for (int i = 0; i < 31; ++i) {
        int m2 = i * 16 + moff;
        if (m2 < M2) {
            float4 w4 = wlds[m2];
            h2 w0 = f2h(w4.x), w1 = f2h(w4.y), w2 = f2h(w4.z), w3 = f2h(w4.w);
            const float2* vp = vbase + (size_t)m2 * C + ci;
#pragma unroll
            for (int cs = 0; cs < 4; ++cs) {
                float2 v = vp[cs * 16];
                h2 vb = f2h(v.x), vs = f2h(v.y);
                accb[0][cs] = FDOT2(w0, vb, accb[0][cs]); accs[0][cs] = FDOT2(w0, vs, accs[0][cs]);
                accb[1][cs] = FDOT2(w1, vb, accb[1][cs]); accs[1][cs] = FDOT2(w1, vs, accs[1][cs]);
                accb[2][cs] = FDOT2(w2, vb, accb[2][cs]); accs[2][cs] = FDOT2(w2, vs, accs[2][cs]);
                accb[3][cs] = FDOT2(w3, vb, accb[3][cs]); accs[3][cs] = FDOT2(w3, vs, accs[3][cs]);
            }
        }
    }
    // reduce over mg (lanes ci, 16+ci, 32+ci, 48+ci), then lane (mg,ci)
    // writes c = mg*16 + ci using slot cs = mg.
#pragma unroll
    for (int li = 0; li < NL; ++li)
#pragma unroll
        for (int cs = 0; cs < 4; ++cs) {
            accb[li][cs] += __shfl_xor(accb[li][cs], 16);
            accb[li][cs] += __shfl_xor(accb[li][cs], 32);
            accs[li][cs] += __shfl_xor(accs[li][cs], 16);
            accs[li][cs] += __shfl_xor(accs[li][cs], 32);
        }
    int cout = (mg << 4) + ci;
#pragma unroll
    for (int li = 0; li < NL; ++li) {
        parts[wv][li][cout][0] = accb[li][mg];
        parts[wv][li][cout][1] = accs[li][mg];
    }
    __syncthreads();

    {
        int li = t & 3, co = t >> 2;       // 256 threads = 4 li x 64 c
        float sb = 0.f, ss = 0.f, rs = 0.f;
#pragma unroll
        for (int w = 0; w < 4; ++w) {
            sb += parts[w][li][co][0];
            ss += parts[w][li][co][1];
            rs += rsp[w][li];
        }
        if (l0 + li < L) {
            float inv = 1.f / rs;
            size_t o = ((size_t)(b * C + co)) * LPAD + l0 + li;
            pbTc[o] = sb * inv;
            psTc[o] = ss * inv;
        }
    }
}

// ---------------------------------------------------------------------------
// Kernel 5: per-(b,c,cell) folded sums. Covering-patch set is constant per
// 8x8 cell, so precompute {back,std}/cnt once per cell.
// ---------------------------------------------------------------------------
__global__ __launch_bounds__(256) void fold_kernel(
    const float* __restrict__ pbTc, const float* __restrict__ psTc,
    float2* __restrict__ fold)
{
    int idx = blockIdx.x * 256 + threadIdx.x;   // bc*1024 + cell
    int cell = idx & 1023, bc = idx >> 10;
    int hq = cell >> 5, wq = cell & 31;
    int ph0 = hq > 0 ? hq - 1 : 0;
    int ph1 = hq < NUMS ? hq : NUMS - 1;
    int pw0 = wq > 0 ? wq - 1 : 0;
    int pw1 = wq < NUMS ? wq : NUMS - 1;
    const float* pbc = pbTc + (size_t)bc * LPAD;
    const float* psc = psTc + (size_t)bc * LPAD;
    float sb = 0.f, ss = 0.f;
    for (int ph = ph0; ph <= ph1; ++ph) {
        int base = ph * 31;
        for (int pw = pw0; pw <= pw1; ++pw) {
            sb += pbc[base + pw];
            ss += psc[base + pw];
        }
    }
    float rc = 1.f / (float)((ph1 - ph0 + 1) * (pw1 - pw0 + 1));
    fold[idx] = make_float2(sb * rc, ss * rc);
}

// ---------------------------------------------------------------------------
// Kernel 6: fused epilogue — pure streaming now (x, mask, 1 float2/cell, out).
// ---------------------------------------------------------------------------
__global__ __launch_bounds__(256) void out_kernel(
    const float* __restrict__ x, const float* __restrict__ mask,
    const float* __restrict__ stats, const float2* __restrict__ fold,
    const float* __restrict__ fgg, const float* __restrict__ fgb,
    const float* __restrict__ bgg, const float* __restrict__ bgb,
    float* __restrict__ out)
{
    int idx = blockIdx.x * 256 + threadIdx.x;   // one float4 each
    int w4 = idx & (W / 4 - 1);
    int rest = idx >> 6;
    int h = rest & (H - 1);
    int bc = rest >> 8;
    int c = bc & (C - 1);
    int b = bc >> 6;
    int w = w4 * 4;

    size_t pix = ((size_t)bc * H + h) * W + w;
    float4 xv = *(const float4*)&x[pix];
    float4 mv = *(const float4*)&mask[((size_t)b * H + h) * W + w];

    const float* st = stats + (size_t)bc * 4;
    float mu_f = st[2], isf = st[3];

    int cell = ((h >> 3) << 5) + (w >> 3);
    float2 f = fold[(size_t)bc * 1024 + cell];
    float fback = f.x, fstd = f.y;

    float ga = 1.f + fgg[c], be = fgb[c];
    float gb_ = 1.f + bgg[c], bb = bgb[c];

    float xs[4] = {xv.x, xv.y, xv.z, xv.w};
    float ms_[4] = {mv.x, mv.y, mv.z, mv.w};
    float4 res;
    float* rp = &res.x;
#pragma unroll
    for (int j = 0; j < 4; ++j) {
        float nfg_px = (xs[j] - mu_f) * isf * ms_[j];
        float nf = nfg_px * fstd + fback;
        rp[j] = (nf * ga + be) * ms_[j] + (xs[j] * gb_ + bb) * (1.f - ms_[j]);
    }
    *(float4*)&out[pix] = res;
}

// ---------------------------------------------------------------------------
extern "C" void kernel_launch(void* const* d_in, const int* in_sizes, int n_in,
                              void* d_out, int out_size, void* d_ws, size_t ws_size,
                              hipStream_t stream)
{
    const float* x    = (const float*)d_in[0];
    const float* mask = (const float*)d_in[1];
    const float* fgg  = (const float*)d_in[2];
    const float* fgb  = (const float*)d_in[3];
    const float* bgg  = (const float*)d_in[4];
    const float* bgb  = (const float*)d_in[5];
    const float* qg   = (const float*)d_in[6];
    const float* qb   = (const float*)d_in[7];
    const float* kg   = (const float*)d_in[8];
    const float* kb   = (const float*)d_in[9];
    const float* bt   = (const float*)d_in[10];
    float* out = (float*)d_out;

    float* ws = (float*)d_ws;
    float4* cellsA = (float4*)ws;                        // B*1024*C float4
    float* cellsM  = ws + (size_t)B * 1024 * C * 4;      // 2048 f
    float* stats   = cellsM + (size_t)B * 1024;          // 512 f
    float* qTT     = stats + (size_t)B * C * 4;          // B*C*LPAD
    float* kTT     = qTT + (size_t)B * C * LPAD;         // B*C*MPAD
    float2* mvh    = (float2*)(kTT + (size_t)B * C * MPAD); // B*M2*C float2
    float* pbTc    = (float*)mvh + (size_t)B * M2 * C * 2;  // B*C*LPAD
    float* psTc    = pbTc + (size_t)B * C * LPAD;           // B*C*LPAD
    float2* fold   = (float2*)(psTc + (size_t)B * C * LPAD); // B*C*1024 float2

    cellsum_kernel<<<dim3(32, C, B), 256, 0, stream>>>(x, mask, cellsA, cellsM);
    stats_kernel<<<dim3(C, B), 256, 0, stream>>>(cellsA, cellsM, stats);
    patchfinal_kernel<<<dim3(241, B), 256, 0, stream>>>(
        cellsA, cellsM, stats, qg, qb, kg, kb, qTT, kTT, mvh);
    attn_kernel<<<dim3(NGROUP, B), 256, 0, stream>>>(qTT, kTT, mvh, bt, pbTc, psTc);
    fold_kernel<<<(B * C * 1024) / 256, 256, 0, stream>>>(pbTc, psTc, fold);
    out_kernel<<<(B * C * H * W / 4 + 255) / 256, 256, 0, stream>>>(
        x, mask, stats, fold, fgg, fgb, bgg, bgb, out);
}